// Round 6
// baseline (370.122 us; speedup 1.0000x reference)
//
#include <hip/hip_runtime.h>

static constexpr int NN   = 100000;   // nodes
static constexpr int NE   = 1600000;  // edges (without self loops)
static constexpr int ET   = NE + NN;  // edges + self loops
static constexpr int NG   = 512;      // graphs
static constexpr int INF_ = 16;
static constexpr int HID  = 64;
static constexpr int BKT_SH = 7;                       // 128 nodes / bucket
static constexpr int NBKT = (NN + 127) / 128;          // 782 buckets
static constexpr int NCH  = 256;                       // edge chunks (counting sort)
static constexpr int CHUNK = (ET + NCH - 1) / NCH;     // 6641 edges / chunk
static constexpr int M_   = NBKT * NCH;                // counts matrix, 200192
static constexpr int SBLK = (M_ + 1023) / 1024;        // scan blocks (196)
#define NEG_SLOPE 0.2f

__device__ __forceinline__ float lrelu(float x) { return x > 0.f ? x : NEG_SLOPE * x; }

// ---------- layer-1 node transform: h = relu(x) @ W1, a_src/a_dst dots ----------
__global__ __launch_bounds__(256) void k_node1(
    const float* __restrict__ x, const float* __restrict__ W,
    const float* __restrict__ atts, const float* __restrict__ attd,
    float* __restrict__ h, float* __restrict__ a_s, float* __restrict__ a_d)
{
  __shared__ float Ws[INF_][HID];
  __shared__ float xs[4][INF_];
  const int tid = threadIdx.x;
  for (int i = tid; i < INF_ * HID; i += 256) Ws[i / HID][i % HID] = W[i];
  const int wv = tid >> 6, ln = tid & 63;
  const int n = blockIdx.x * 4 + wv;
  if (ln < INF_) {
    float v = x[n * INF_ + ln];
    xs[wv][ln] = v > 0.f ? v : 0.f;
  }
  __syncthreads();
  float acc = 0.f;
#pragma unroll
  for (int k = 0; k < INF_; ++k) acc += xs[wv][k] * Ws[k][ln];
  h[n * HID + ln] = acc;
  float as = acc * atts[ln], ad = acc * attd[ln];
#pragma unroll
  for (int o = 32; o > 0; o >>= 1) { as += __shfl_xor(as, o); ad += __shfl_xor(ad, o); }
  if (ln == 0) { a_s[n] = as; a_d[n] = ad; }
}

// ---------- layer-2 node transform: h2 = act1 @ W2 (act1 already relu'd) ----------
__global__ __launch_bounds__(256) void k_node2(
    const float* __restrict__ act, const float* __restrict__ W,
    const float* __restrict__ atts, const float* __restrict__ attd,
    float* __restrict__ h, float* __restrict__ a_s, float* __restrict__ a_d)
{
  __shared__ float Ws[HID][HID];   // 16 KB
  __shared__ float xs[4][HID];
  const int tid = threadIdx.x;
  for (int i = tid; i < HID * HID; i += 256) Ws[i / HID][i % HID] = W[i];
  const int wv = tid >> 6, ln = tid & 63;
  const int n = blockIdx.x * 4 + wv;
  xs[wv][ln] = act[n * HID + ln];
  __syncthreads();
  float acc = 0.f;
#pragma unroll
  for (int k = 0; k < HID; ++k) acc += xs[wv][k] * Ws[k][ln];
  h[n * HID + ln] = acc;
  float as = acc * atts[ln], ad = acc * attd[ln];
#pragma unroll
  for (int o = 32; o > 0; o >>= 1) { as += __shfl_xor(as, o); ad += __shfl_xor(ad, o); }
  if (ln == 0) { a_s[n] = as; a_d[n] = ad; }
}

// ---------- counting sort pass A: per-chunk bucket histogram ----------
__global__ __launch_bounds__(256) void k_cnt(const int* __restrict__ ei,
                                             unsigned* __restrict__ counts)
{
  __shared__ unsigned lc[NBKT];
  for (int i = threadIdx.x; i < NBKT; i += 256) lc[i] = 0;
  __syncthreads();
  const int b = blockIdx.x;
  const int beg = b * CHUNK, end = min(ET, beg + CHUNK);
  for (int e = beg + threadIdx.x; e < end; e += 256) {
    int d = (e < NE) ? ei[NE + e] : e - NE;
    atomicAdd(&lc[d >> BKT_SH], 1u);
  }
  __syncthreads();
  for (int k = threadIdx.x; k < NBKT; k += 256) counts[k * NCH + b] = lc[k];
}

// ---------- scan pass 1: 1024-elem block sums over counts ----------
__global__ __launch_bounds__(256) void k_scan1(const unsigned* __restrict__ counts,
                                               unsigned* __restrict__ bsums)
{
  __shared__ unsigned red[4];
  const int t = threadIdx.x;
  const int base = blockIdx.x * 1024 + t * 4;
  unsigned s = 0;
#pragma unroll
  for (int k = 0; k < 4; ++k) { int i = base + k; if (i < M_) s += counts[i]; }
#pragma unroll
  for (int o = 32; o > 0; o >>= 1) s += __shfl_xor(s, o);
  if ((t & 63) == 0) red[t >> 6] = s;
  __syncthreads();
  if (t == 0) bsums[blockIdx.x] = red[0] + red[1] + red[2] + red[3];
}

// ---------- scan pass 2: exclusive scan of block sums (single wave) ----------
__global__ __launch_bounds__(64) void k_scan2(unsigned* __restrict__ bsums)
{
  const int ln = threadIdx.x;
  unsigned carry = 0;
  for (int base = 0; base < SBLK; base += 64) {
    int i = base + ln;
    unsigned orig = (i < SBLK) ? bsums[i] : 0;
    unsigned v = orig;
#pragma unroll
    for (int o = 1; o < 64; o <<= 1) { unsigned tv = __shfl_up(v, o); if (ln >= o) v += tv; }
    if (i < SBLK) bsums[i] = carry + v - orig;
    carry += __shfl(v, 63);
  }
}

// ---------- scan pass 3: add-back, exclusive scan in place ----------
__global__ __launch_bounds__(256) void k_scan3(unsigned* __restrict__ counts,
                                               const unsigned* __restrict__ bsums)
{
  __shared__ unsigned wsum[4];
  const int t = threadIdx.x;
  const int base = blockIdx.x * 1024 + t * 4;
  unsigned d[4]; unsigned s = 0;
#pragma unroll
  for (int k = 0; k < 4; ++k) { int i = base + k; d[k] = (i < M_) ? counts[i] : 0; s += d[k]; }
  unsigned v = s;
#pragma unroll
  for (int o = 1; o < 64; o <<= 1) { unsigned tv = __shfl_up(v, o); if ((t & 63) >= o) v += tv; }
  if ((t & 63) == 63) wsum[t >> 6] = v;
  __syncthreads();
  unsigned woff = 0;
  for (int w = 0; w < (t >> 6); ++w) woff += wsum[w];
  unsigned excl = woff + (v - s) + bsums[blockIdx.x];
#pragma unroll
  for (int k = 0; k < 4; ++k) {
    int i = base + k;
    if (i < M_) counts[i] = excl;
    excl += d[k];
  }
}

// ---------- counting sort pass C: place pairs (LDS cursors, no global atomics) ----------
__global__ __launch_bounds__(256) void k_place(const int* __restrict__ ei,
                                               const unsigned* __restrict__ S,
                                               int2* __restrict__ pairs)
{
  __shared__ unsigned cur[NBKT];
  const int b = blockIdx.x;
  for (int k = threadIdx.x; k < NBKT; k += 256) cur[k] = S[k * NCH + b];
  __syncthreads();
  const int beg = b * CHUNK, end = min(ET, beg + CHUNK);
  for (int e = beg + threadIdx.x; e < end; e += 256) {
    int s, d;
    if (e < NE) { s = ei[e]; d = ei[NE + e]; } else { s = d = e - NE; }
    unsigned pos = atomicAdd(&cur[d >> BKT_SH], 1u);
    pairs[pos] = make_int2(s, d);
  }
}

// ---------- per-bucket fine CSR build (reads scanned matrix directly) ----------
__global__ __launch_bounds__(256) void k_bcsr(const int2* __restrict__ pairs,
                                              const unsigned* __restrict__ S,
                                              unsigned* __restrict__ rowptr,
                                              unsigned* __restrict__ deg,
                                              int* __restrict__ es)
{
  __shared__ unsigned cnt[128], cur[128], wtot[2];
  const int b = blockIdx.x, t = threadIdx.x;
  const unsigned base = S[b * NCH];
  const unsigned m = ((b + 1 < NBKT) ? S[(b + 1) * NCH] : (unsigned)ET) - base;
  if (t < 128) cnt[t] = 0;
  __syncthreads();
  for (unsigned j = t; j < m; j += 256)
    atomicAdd(&cnt[pairs[base + j].y & 127], 1u);
  __syncthreads();
  unsigned c = 0, v = 0;
  if (t < 128) {
    c = cnt[t]; v = c;
    const int ln = t & 63;
#pragma unroll
    for (int o = 1; o < 64; o <<= 1) { unsigned tv = __shfl_up(v, o); if (ln >= o) v += tv; }
    if (ln == 63) wtot[t >> 6] = v;
  }
  __syncthreads();
  if (t < 128) {
    unsigned excl = v - c + ((t >= 64) ? wtot[0] : 0);
    cur[t] = excl;
    int node = (b << BKT_SH) + t;
    if (node < NN) { rowptr[node] = base + excl; deg[node] = c; }
  }
  __syncthreads();
  for (unsigned j = t; j < m; j += 256) {
    int2 p = pairs[base + j];
    unsigned pos = atomicAdd(&cur[p.y & 127], 1u);
    es[base + pos] = p.x;
  }
}

// ---------- attention: per-node max/den, write normalized alpha per edge ----------
__global__ __launch_bounds__(256) void k_attn(
    const int* __restrict__ es, const unsigned* __restrict__ rowptr,
    const unsigned* __restrict__ deg, const float* __restrict__ a_s,
    const float* __restrict__ a_d, float* __restrict__ alpha)
{
  const int wv = threadIdx.x >> 6, ln = threadIdx.x & 63;
  const int n = blockIdx.x * 4 + wv;
  const unsigned beg = rowptr[n], dg = deg[n];
  const float ad = a_d[n];
  const unsigned j0 = beg + (unsigned)ln;
  // first chunk cached in regs (deg<=64 always in practice; loops cover the rest)
  float l0 = -1e30f, m = -1e30f;
  if ((unsigned)ln < dg) { l0 = lrelu(a_s[es[j0]] + ad); m = l0; }
  for (unsigned j = beg + 64 + ln; j < beg + dg; j += 64)
    m = fmaxf(m, lrelu(a_s[es[j]] + ad));
#pragma unroll
  for (int o = 32; o > 0; o >>= 1) m = fmaxf(m, __shfl_xor(m, o));
  float ev0 = ((unsigned)ln < dg) ? __expf(l0 - m) : 0.f;
  float den = ev0;
  for (unsigned j = beg + 64 + ln; j < beg + dg; j += 64)
    den += __expf(lrelu(a_s[es[j]] + ad) - m);
#pragma unroll
  for (int o = 32; o > 0; o >>= 1) den += __shfl_xor(den, o);
  const float inv = 1.f / (den + 1e-16f);
  if ((unsigned)ln < dg) alpha[j0] = ev0 * inv;
  for (unsigned j = beg + 64 + ln; j < beg + dg; j += 64)
    alpha[j] = __expf(lrelu(a_s[es[j]] + ad) - m) * inv;
}

// ---------- weighted SpMM: wave per dst node, 16 edges x 4 lanes ----------
__global__ __launch_bounds__(256) void k_wsum(
    const int* __restrict__ es, const float* __restrict__ alpha,
    const unsigned* __restrict__ rowptr, const unsigned* __restrict__ deg,
    const float* __restrict__ h, const float* __restrict__ bias,
    float* __restrict__ act)
{
  const int wv = threadIdx.x >> 6, ln = threadIdx.x & 63;
  const int n = blockIdx.x * 4 + wv;
  const unsigned beg = rowptr[n];
  const unsigned end = beg + deg[n];
  const int e16 = ln >> 2, q = ln & 3;
  float a[16];
#pragma unroll
  for (int k = 0; k < 16; ++k) a[k] = 0.f;

  for (unsigned c = beg; c < end; c += 16) {
    int s_st = 0; float al_st = 0.f;
    {
      unsigned j = c + (unsigned)ln;
      if (ln < 16 && j < end) { s_st = es[j]; al_st = alpha[j]; }
    }
    int   s  = __shfl(s_st, e16);
    float al = __shfl(al_st, e16);
    if (c + (unsigned)e16 < end) {
      const float4* hp = (const float4*)(h + (size_t)s * HID + q * 16);
      float4 h0 = hp[0], h1 = hp[1], h2 = hp[2], h3 = hp[3];
      a[0]  += al * h0.x; a[1]  += al * h0.y; a[2]  += al * h0.z; a[3]  += al * h0.w;
      a[4]  += al * h1.x; a[5]  += al * h1.y; a[6]  += al * h1.z; a[7]  += al * h1.w;
      a[8]  += al * h2.x; a[9]  += al * h2.y; a[10] += al * h2.z; a[11] += al * h2.w;
      a[12] += al * h3.x; a[13] += al * h3.y; a[14] += al * h3.z; a[15] += al * h3.w;
    }
  }
  // reduce acc across the 16 edge-groups (strides 4..32)
#pragma unroll
  for (int o = 4; o < 64; o <<= 1) {
#pragma unroll
    for (int k = 0; k < 16; ++k) a[k] += __shfl_xor(a[k], o);
  }
  if (ln < 4) {   // lane ln holds features [ln*16, ln*16+16)
    float4* op = (float4*)(act + (size_t)n * HID + ln * 16);
    const float4* bp = (const float4*)(bias + ln * 16);
#pragma unroll
    for (int k = 0; k < 4; ++k) {
      float4 b4 = bp[k];
      float4 v;
      v.x = a[4 * k + 0] + b4.x;
      v.y = a[4 * k + 1] + b4.y;
      v.z = a[4 * k + 2] + b4.z;
      v.w = a[4 * k + 3] + b4.w;
      v.x = v.x > 0.f ? v.x : 0.f;
      v.y = v.y > 0.f ? v.y : 0.f;
      v.z = v.z > 0.f ? v.z : 0.f;
      v.w = v.w > 0.f ? v.w : 0.f;
      op[k] = v;
    }
  }
}

// ---------- pooling: per-graph max/sum over finalized act2 ----------
__global__ __launch_bounds__(256) void k_pool(
    const float* __restrict__ act, const int* __restrict__ batch,
    unsigned* __restrict__ gmax, float* __restrict__ gsum, unsigned* __restrict__ cnt)
{
  const int wv = threadIdx.x >> 6, ln = threadIdx.x & 63;
  const int base = (blockIdx.x * 4 + wv) * 64;
  if (base >= NN) return;
  const int end = min(NN, base + 64);
  float rmax = 0.f, rsum = 0.f;
  int cg = batch[base], run = 0;
  for (int n = base; n < end; ++n) {
    int g = batch[n];
    if (g != cg) {
      atomicMax(&gmax[cg * HID + ln], __float_as_uint(rmax));  // relu -> >=0
      unsafeAtomicAdd(&gsum[cg * HID + ln], rsum);
      if (ln == 0) atomicAdd(&cnt[cg], (unsigned)run);
      rmax = 0.f; rsum = 0.f; run = 0; cg = g;
    }
    float v = act[n * HID + ln];
    rmax = fmaxf(rmax, v); rsum += v; ++run;
  }
  atomicMax(&gmax[cg * HID + ln], __float_as_uint(rmax));
  unsafeAtomicAdd(&gsum[cg * HID + ln], rsum);
  if (ln == 0) atomicAdd(&cnt[cg], (unsigned)run);
}

// ---------- head: [gmax | gmean] @ fc_w + fc_b ----------
__global__ __launch_bounds__(256) void k_final(
    const unsigned* __restrict__ gmax, const float* __restrict__ gsum,
    const unsigned* __restrict__ cnt, const float* __restrict__ fcw,
    const float* __restrict__ fcb, float* __restrict__ out)
{
  const int wv = threadIdx.x >> 6, ln = threadIdx.x & 63;
  const int g = blockIdx.x * 4 + wv;
  if (g >= NG) return;
  float c = (float)cnt[g];
  float mx = __uint_as_float(gmax[g * HID + ln]);
  float mean = gsum[g * HID + ln] / fmaxf(c, 1.f);
  float v = mx * fcw[ln] + mean * fcw[HID + ln];
#pragma unroll
  for (int o = 32; o > 0; o >>= 1) v += __shfl_xor(v, o);
  if (ln == 0) out[g] = v + fcb[0];
}

extern "C" void kernel_launch(void* const* d_in, const int* in_sizes, int n_in,
                              void* d_out, int out_size, void* d_ws, size_t ws_size,
                              hipStream_t stream)
{
  const float* x    = (const float*)d_in[0];
  const int*   ei   = (const int*)d_in[1];
  const int*   batch= (const int*)d_in[2];
  const float* W1   = (const float*)d_in[3];
  const float* as1  = (const float*)d_in[4];
  const float* ad1  = (const float*)d_in[5];
  const float* b1   = (const float*)d_in[6];
  const float* W2   = (const float*)d_in[7];
  const float* as2  = (const float*)d_in[8];
  const float* ad2  = (const float*)d_in[9];
  const float* b2   = (const float*)d_in[10];
  const float* fcw  = (const float*)d_in[11];
  const float* fcb  = (const float*)d_in[12];
  float* out = (float*)d_out;

  float* h        = (float*)d_ws;                  // NN*HID
  float* act      = h + (size_t)NN * HID;          // NN*HID
  float* a_s      = act + (size_t)NN * HID;        // NN
  float* a_d      = a_s + NN;                      // NN
  unsigned* deg   = (unsigned*)(a_d + NN);         // NN
  unsigned* rowptr= deg + NN;                      // NN
  unsigned* counts= rowptr + NN;                   // M_ (pad to 200704)
  unsigned* bsums = counts + 200704;               // SBLK (pad 256)
  int* es         = (int*)(bsums + 256);           // ET
  float* alpha    = (float*)(es + ET);             // ET
  unsigned* gmax  = (unsigned*)(alpha + ET);       // NG*HID
  float* gsum     = (float*)(gmax + NG * HID);     // NG*HID
  unsigned* cnt   = (unsigned*)(gsum + NG * HID);  // NG
  // pairs staging aliases h/act (13.6MB <= 51.2MB); consumed before k_node1 writes h
  int2* pairs     = (int2*)h;

  // ---- CSR build via contention-free counting sort (topology shared) ----
  k_cnt  <<<NCH, 256, 0, stream>>>(ei, counts);
  k_scan1<<<SBLK, 256, 0, stream>>>(counts, bsums);
  k_scan2<<<1, 64, 0, stream>>>(bsums);
  k_scan3<<<SBLK, 256, 0, stream>>>(counts, bsums);
  k_place<<<NCH, 256, 0, stream>>>(ei, counts, pairs);
  k_bcsr <<<NBKT, 256, 0, stream>>>(pairs, counts, rowptr, deg, es);

  // ---- layer 1 ----
  k_node1<<<NN / 4, 256, 0, stream>>>(x, W1, as1, ad1, h, a_s, a_d);
  k_attn <<<NN / 4, 256, 0, stream>>>(es, rowptr, deg, a_s, a_d, alpha);
  k_wsum <<<NN / 4, 256, 0, stream>>>(es, alpha, rowptr, deg, h, b1, act);

  // ---- layer 2 ----
  k_node2<<<NN / 4, 256, 0, stream>>>(act, W2, as2, ad2, h, a_s, a_d);
  k_attn <<<NN / 4, 256, 0, stream>>>(es, rowptr, deg, a_s, a_d, alpha);
  k_wsum <<<NN / 4, 256, 0, stream>>>(es, alpha, rowptr, deg, h, b2, act);

  // ---- pooling + head ----
  hipMemsetAsync(gmax, 0, sizeof(unsigned) * NG * HID, stream);
  hipMemsetAsync(gsum, 0, sizeof(float) * NG * HID, stream);
  hipMemsetAsync(cnt,  0, sizeof(unsigned) * NG, stream);
  k_pool<<<(NN + 255) / 256, 256, 0, stream>>>(act, batch, gmax, gsum, cnt);
  k_final<<<NG / 4, 256, 0, stream>>>(gmax, gsum, cnt, fcw, fcb, out);
}

// Round 7
// 368.539 us; speedup vs baseline: 1.0043x; 1.0043x over previous
//
#include <hip/hip_runtime.h>

static constexpr int NN   = 100000;   // nodes
static constexpr int NE   = 1600000;  // edges (without self loops)
static constexpr int ET   = NE + NN;  // edges + self loops
static constexpr int NG   = 512;      // graphs
static constexpr int INF_ = 16;
static constexpr int HID  = 64;
static constexpr int BKT_SH = 7;                       // 128 nodes / bucket
static constexpr int NBKT = (NN + 127) / 128;          // 782 buckets
static constexpr int NCH  = 256;                       // edge chunks (counting sort)
static constexpr int CHUNK = (ET + NCH - 1) / NCH;     // 6641 edges / chunk
static constexpr int M_   = NBKT * NCH;                // counts matrix, 200192
static constexpr int SBLK = (M_ + 1023) / 1024;        // scan blocks (196)
#define NEG_SLOPE 0.2f

__device__ __forceinline__ float lrelu(float x) { return x > 0.f ? x : NEG_SLOPE * x; }

// ---------- layer-1 node transform: h = relu(x) @ W1, a_src/a_dst dots ----------
__global__ __launch_bounds__(256) void k_node1(
    const float* __restrict__ x, const float* __restrict__ W,
    const float* __restrict__ atts, const float* __restrict__ attd,
    float* __restrict__ h, float* __restrict__ a_s, float* __restrict__ a_d)
{
  __shared__ float Ws[INF_][HID];
  __shared__ float xs[4][INF_];
  const int tid = threadIdx.x;
  for (int i = tid; i < INF_ * HID; i += 256) Ws[i / HID][i % HID] = W[i];
  const int wv = tid >> 6, ln = tid & 63;
  const int n = blockIdx.x * 4 + wv;
  if (ln < INF_) {
    float v = x[n * INF_ + ln];
    xs[wv][ln] = v > 0.f ? v : 0.f;
  }
  __syncthreads();
  float acc = 0.f;
#pragma unroll
  for (int k = 0; k < INF_; ++k) acc += xs[wv][k] * Ws[k][ln];
  h[n * HID + ln] = acc;
  float as = acc * atts[ln], ad = acc * attd[ln];
#pragma unroll
  for (int o = 32; o > 0; o >>= 1) { as += __shfl_xor(as, o); ad += __shfl_xor(ad, o); }
  if (ln == 0) { a_s[n] = as; a_d[n] = ad; }
}

// ---------- layer-2 node transform: h2 = act1 @ W2 (act1 already relu'd) ----------
__global__ __launch_bounds__(256) void k_node2(
    const float* __restrict__ act, const float* __restrict__ W,
    const float* __restrict__ atts, const float* __restrict__ attd,
    float* __restrict__ h, float* __restrict__ a_s, float* __restrict__ a_d)
{
  __shared__ float Ws[HID][HID];   // 16 KB
  __shared__ float xs[4][HID];
  const int tid = threadIdx.x;
  for (int i = tid; i < HID * HID; i += 256) Ws[i / HID][i % HID] = W[i];
  const int wv = tid >> 6, ln = tid & 63;
  const int n = blockIdx.x * 4 + wv;
  xs[wv][ln] = act[n * HID + ln];
  __syncthreads();
  float acc = 0.f;
#pragma unroll
  for (int k = 0; k < HID; ++k) acc += xs[wv][k] * Ws[k][ln];
  h[n * HID + ln] = acc;
  float as = acc * atts[ln], ad = acc * attd[ln];
#pragma unroll
  for (int o = 32; o > 0; o >>= 1) { as += __shfl_xor(as, o); ad += __shfl_xor(ad, o); }
  if (ln == 0) { a_s[n] = as; a_d[n] = ad; }
}

// ---------- counting sort pass A: per-chunk bucket histogram ----------
__global__ __launch_bounds__(256) void k_cnt(const int* __restrict__ ei,
                                             unsigned* __restrict__ counts)
{
  __shared__ unsigned lc[NBKT];
  for (int i = threadIdx.x; i < NBKT; i += 256) lc[i] = 0;
  __syncthreads();
  const int b = blockIdx.x;
  const int beg = b * CHUNK, end = min(ET, beg + CHUNK);
  for (int e = beg + threadIdx.x; e < end; e += 256) {
    int d = (e < NE) ? ei[NE + e] : e - NE;
    atomicAdd(&lc[d >> BKT_SH], 1u);
  }
  __syncthreads();
  for (int k = threadIdx.x; k < NBKT; k += 256) counts[k * NCH + b] = lc[k];
}

// ---------- scan pass 1: 1024-elem block sums over counts ----------
__global__ __launch_bounds__(256) void k_scan1(const unsigned* __restrict__ counts,
                                               unsigned* __restrict__ bsums)
{
  __shared__ unsigned red[4];
  const int t = threadIdx.x;
  const int base = blockIdx.x * 1024 + t * 4;
  unsigned s = 0;
#pragma unroll
  for (int k = 0; k < 4; ++k) { int i = base + k; if (i < M_) s += counts[i]; }
#pragma unroll
  for (int o = 32; o > 0; o >>= 1) s += __shfl_xor(s, o);
  if ((t & 63) == 0) red[t >> 6] = s;
  __syncthreads();
  if (t == 0) bsums[blockIdx.x] = red[0] + red[1] + red[2] + red[3];
}

// ---------- scan pass 2: exclusive scan of block sums (single wave) ----------
__global__ __launch_bounds__(64) void k_scan2(unsigned* __restrict__ bsums)
{
  const int ln = threadIdx.x;
  unsigned carry = 0;
  for (int base = 0; base < SBLK; base += 64) {
    int i = base + ln;
    unsigned orig = (i < SBLK) ? bsums[i] : 0;
    unsigned v = orig;
#pragma unroll
    for (int o = 1; o < 64; o <<= 1) { unsigned tv = __shfl_up(v, o); if (ln >= o) v += tv; }
    if (i < SBLK) bsums[i] = carry + v - orig;
    carry += __shfl(v, 63);
  }
}

// ---------- scan pass 3: add-back, exclusive scan in place ----------
__global__ __launch_bounds__(256) void k_scan3(unsigned* __restrict__ counts,
                                               const unsigned* __restrict__ bsums)
{
  __shared__ unsigned wsum[4];
  const int t = threadIdx.x;
  const int base = blockIdx.x * 1024 + t * 4;
  unsigned d[4]; unsigned s = 0;
#pragma unroll
  for (int k = 0; k < 4; ++k) { int i = base + k; d[k] = (i < M_) ? counts[i] : 0; s += d[k]; }
  unsigned v = s;
#pragma unroll
  for (int o = 1; o < 64; o <<= 1) { unsigned tv = __shfl_up(v, o); if ((t & 63) >= o) v += tv; }
  if ((t & 63) == 63) wsum[t >> 6] = v;
  __syncthreads();
  unsigned woff = 0;
  for (int w = 0; w < (t >> 6); ++w) woff += wsum[w];
  unsigned excl = woff + (v - s) + bsums[blockIdx.x];
#pragma unroll
  for (int k = 0; k < 4; ++k) {
    int i = base + k;
    if (i < M_) counts[i] = excl;
    excl += d[k];
  }
}

// ---------- counting sort pass C: place pairs (LDS cursors, no global atomics) ----------
__global__ __launch_bounds__(256) void k_place(const int* __restrict__ ei,
                                               const unsigned* __restrict__ S,
                                               int2* __restrict__ pairs)
{
  __shared__ unsigned cur[NBKT];
  const int b = blockIdx.x;
  for (int k = threadIdx.x; k < NBKT; k += 256) cur[k] = S[k * NCH + b];
  __syncthreads();
  const int beg = b * CHUNK, end = min(ET, beg + CHUNK);
  for (int e = beg + threadIdx.x; e < end; e += 256) {
    int s, d;
    if (e < NE) { s = ei[e]; d = ei[NE + e]; } else { s = d = e - NE; }
    unsigned pos = atomicAdd(&cur[d >> BKT_SH], 1u);
    pairs[pos] = make_int2(s, d);
  }
}

// ---------- per-bucket fine CSR build (reads scanned matrix directly) ----------
__global__ __launch_bounds__(256) void k_bcsr(const int2* __restrict__ pairs,
                                              const unsigned* __restrict__ S,
                                              unsigned* __restrict__ rowptr,
                                              unsigned* __restrict__ deg,
                                              int* __restrict__ es)
{
  __shared__ unsigned cnt[128], cur[128], wtot[2];
  const int b = blockIdx.x, t = threadIdx.x;
  const unsigned base = S[b * NCH];
  const unsigned m = ((b + 1 < NBKT) ? S[(b + 1) * NCH] : (unsigned)ET) - base;
  if (t < 128) cnt[t] = 0;
  __syncthreads();
  for (unsigned j = t; j < m; j += 256)
    atomicAdd(&cnt[pairs[base + j].y & 127], 1u);
  __syncthreads();
  unsigned c = 0, v = 0;
  if (t < 128) {
    c = cnt[t]; v = c;
    const int ln = t & 63;
#pragma unroll
    for (int o = 1; o < 64; o <<= 1) { unsigned tv = __shfl_up(v, o); if (ln >= o) v += tv; }
    if (ln == 63) wtot[t >> 6] = v;
  }
  __syncthreads();
  if (t < 128) {
    unsigned excl = v - c + ((t >= 64) ? wtot[0] : 0);
    cur[t] = excl;
    int node = (b << BKT_SH) + t;
    if (node < NN) { rowptr[node] = base + excl; deg[node] = c; }
  }
  __syncthreads();
  for (unsigned j = t; j < m; j += 256) {
    int2 p = pairs[base + j];
    unsigned pos = atomicAdd(&cur[p.y & 127], 1u);
    es[base + pos] = p.x;
  }
}

// ---------- attention: per-node max/den, write normalized alpha per edge ----------
__global__ __launch_bounds__(256) void k_attn(
    const int* __restrict__ es, const unsigned* __restrict__ rowptr,
    const unsigned* __restrict__ deg, const float* __restrict__ a_s,
    const float* __restrict__ a_d, float* __restrict__ alpha)
{
  const int wv = threadIdx.x >> 6, ln = threadIdx.x & 63;
  const int n = blockIdx.x * 4 + wv;
  const unsigned beg = rowptr[n], dg = deg[n];
  const float ad = a_d[n];
  const unsigned j0 = beg + (unsigned)ln;
  // first chunk cached in regs (deg<=64 always in practice; loops cover the rest)
  float l0 = -1e30f, m = -1e30f;
  if ((unsigned)ln < dg) { l0 = lrelu(a_s[es[j0]] + ad); m = l0; }
  for (unsigned j = beg + 64 + ln; j < beg + dg; j += 64)
    m = fmaxf(m, lrelu(a_s[es[j]] + ad));
#pragma unroll
  for (int o = 32; o > 0; o >>= 1) m = fmaxf(m, __shfl_xor(m, o));
  float ev0 = ((unsigned)ln < dg) ? __expf(l0 - m) : 0.f;
  float den = ev0;
  for (unsigned j = beg + 64 + ln; j < beg + dg; j += 64)
    den += __expf(lrelu(a_s[es[j]] + ad) - m);
#pragma unroll
  for (int o = 32; o > 0; o >>= 1) den += __shfl_xor(den, o);
  const float inv = 1.f / (den + 1e-16f);
  if ((unsigned)ln < dg) alpha[j0] = ev0 * inv;
  for (unsigned j = beg + 64 + ln; j < beg + dg; j += 64)
    alpha[j] = __expf(lrelu(a_s[es[j]] + ad) - m) * inv;
}

// ---------- weighted SpMM: wave per dst node, 32-edge staged window ----------
// 16 edges x 4 lanes, two edge-sets (A/B) issued back-to-back -> ~2x loads
// in flight per wave (deg<=32 covers >99% of nodes in one burst).
__global__ __launch_bounds__(256) void k_wsum(
    const int* __restrict__ es, const float* __restrict__ alpha,
    const unsigned* __restrict__ rowptr, const unsigned* __restrict__ deg,
    const float* __restrict__ h, const float* __restrict__ bias,
    float* __restrict__ act)
{
  const int wv = threadIdx.x >> 6, ln = threadIdx.x & 63;
  const int n = blockIdx.x * 4 + wv;
  const unsigned beg = rowptr[n];
  const unsigned end = beg + deg[n];
  const int e16 = ln >> 2, q = ln & 3;
  float a[16];
#pragma unroll
  for (int k = 0; k < 16; ++k) a[k] = 0.f;

  for (unsigned c = beg; c < end; c += 32) {
    int s_st = 0; float al_st = 0.f;
    {
      unsigned j = c + (unsigned)ln;
      if (ln < 32 && j < end) { s_st = es[j]; al_st = alpha[j]; }
    }
    const int   sA  = __shfl(s_st, e16);
    const float alA = __shfl(al_st, e16);
    const int   sB  = __shfl(s_st, 16 + e16);
    const float alB = __shfl(al_st, 16 + e16);
    const bool vA = (c + (unsigned)e16) < end;
    const bool vB = (c + 16u + (unsigned)e16) < end;
    float4 a0, a1, a2, a3, b0, b1, b2, b3;
    if (vA) {
      const float4* hp = (const float4*)(h + (size_t)sA * HID + q * 16);
      a0 = hp[0]; a1 = hp[1]; a2 = hp[2]; a3 = hp[3];
    }
    if (vB) {
      const float4* hp = (const float4*)(h + (size_t)sB * HID + q * 16);
      b0 = hp[0]; b1 = hp[1]; b2 = hp[2]; b3 = hp[3];
    }
    if (vA) {
      a[0]  += alA * a0.x; a[1]  += alA * a0.y; a[2]  += alA * a0.z; a[3]  += alA * a0.w;
      a[4]  += alA * a1.x; a[5]  += alA * a1.y; a[6]  += alA * a1.z; a[7]  += alA * a1.w;
      a[8]  += alA * a2.x; a[9]  += alA * a2.y; a[10] += alA * a2.z; a[11] += alA * a2.w;
      a[12] += alA * a3.x; a[13] += alA * a3.y; a[14] += alA * a3.z; a[15] += alA * a3.w;
    }
    if (vB) {
      a[0]  += alB * b0.x; a[1]  += alB * b0.y; a[2]  += alB * b0.z; a[3]  += alB * b0.w;
      a[4]  += alB * b1.x; a[5]  += alB * b1.y; a[6]  += alB * b1.z; a[7]  += alB * b1.w;
      a[8]  += alB * b2.x; a[9]  += alB * b2.y; a[10] += alB * b2.z; a[11] += alB * b2.w;
      a[12] += alB * b3.x; a[13] += alB * b3.y; a[14] += alB * b3.z; a[15] += alB * b3.w;
    }
  }
  // reduce acc across the 16 edge-groups (strides 4..32)
#pragma unroll
  for (int o = 4; o < 64; o <<= 1) {
#pragma unroll
    for (int k = 0; k < 16; ++k) a[k] += __shfl_xor(a[k], o);
  }
  if (ln < 4) {   // lane ln holds features [ln*16, ln*16+16)
    float4* op = (float4*)(act + (size_t)n * HID + ln * 16);
    const float4* bp = (const float4*)(bias + ln * 16);
#pragma unroll
    for (int k = 0; k < 4; ++k) {
      float4 b4 = bp[k];
      float4 v;
      v.x = a[4 * k + 0] + b4.x;
      v.y = a[4 * k + 1] + b4.y;
      v.z = a[4 * k + 2] + b4.z;
      v.w = a[4 * k + 3] + b4.w;
      v.x = v.x > 0.f ? v.x : 0.f;
      v.y = v.y > 0.f ? v.y : 0.f;
      v.z = v.z > 0.f ? v.z : 0.f;
      v.w = v.w > 0.f ? v.w : 0.f;
      op[k] = v;
    }
  }
}

// ---------- pooling: per-graph max/sum over finalized act2 ----------
__global__ __launch_bounds__(256) void k_pool(
    const float* __restrict__ act, const int* __restrict__ batch,
    unsigned* __restrict__ gmax, float* __restrict__ gsum, unsigned* __restrict__ cnt)
{
  const int wv = threadIdx.x >> 6, ln = threadIdx.x & 63;
  const int base = (blockIdx.x * 4 + wv) * 64;
  if (base >= NN) return;
  const int end = min(NN, base + 64);
  float rmax = 0.f, rsum = 0.f;
  int cg = batch[base], run = 0;
  for (int n = base; n < end; ++n) {
    int g = batch[n];
    if (g != cg) {
      atomicMax(&gmax[cg * HID + ln], __float_as_uint(rmax));  // relu -> >=0
      unsafeAtomicAdd(&gsum[cg * HID + ln], rsum);
      if (ln == 0) atomicAdd(&cnt[cg], (unsigned)run);
      rmax = 0.f; rsum = 0.f; run = 0; cg = g;
    }
    float v = act[n * HID + ln];
    rmax = fmaxf(rmax, v); rsum += v; ++run;
  }
  atomicMax(&gmax[cg * HID + ln], __float_as_uint(rmax));
  unsafeAtomicAdd(&gsum[cg * HID + ln], rsum);
  if (ln == 0) atomicAdd(&cnt[cg], (unsigned)run);
}

// ---------- head: [gmax | gmean] @ fc_w + fc_b ----------
__global__ __launch_bounds__(256) void k_final(
    const unsigned* __restrict__ gmax, const float* __restrict__ gsum,
    const unsigned* __restrict__ cnt, const float* __restrict__ fcw,
    const float* __restrict__ fcb, float* __restrict__ out)
{
  const int wv = threadIdx.x >> 6, ln = threadIdx.x & 63;
  const int g = blockIdx.x * 4 + wv;
  if (g >= NG) return;
  float c = (float)cnt[g];
  float mx = __uint_as_float(gmax[g * HID + ln]);
  float mean = gsum[g * HID + ln] / fmaxf(c, 1.f);
  float v = mx * fcw[ln] + mean * fcw[HID + ln];
#pragma unroll
  for (int o = 32; o > 0; o >>= 1) v += __shfl_xor(v, o);
  if (ln == 0) out[g] = v + fcb[0];
}

extern "C" void kernel_launch(void* const* d_in, const int* in_sizes, int n_in,
                              void* d_out, int out_size, void* d_ws, size_t ws_size,
                              hipStream_t stream)
{
  const float* x    = (const float*)d_in[0];
  const int*   ei   = (const int*)d_in[1];
  const int*   batch= (const int*)d_in[2];
  const float* W1   = (const float*)d_in[3];
  const float* as1  = (const float*)d_in[4];
  const float* ad1  = (const float*)d_in[5];
  const float* b1   = (const float*)d_in[6];
  const float* W2   = (const float*)d_in[7];
  const float* as2  = (const float*)d_in[8];
  const float* ad2  = (const float*)d_in[9];
  const float* b2   = (const float*)d_in[10];
  const float* fcw  = (const float*)d_in[11];
  const float* fcb  = (const float*)d_in[12];
  float* out = (float*)d_out;

  float* h        = (float*)d_ws;                  // NN*HID
  float* act      = h + (size_t)NN * HID;          // NN*HID
  float* a_s      = act + (size_t)NN * HID;        // NN
  float* a_d      = a_s + NN;                      // NN
  unsigned* deg   = (unsigned*)(a_d + NN);         // NN
  unsigned* rowptr= deg + NN;                      // NN
  unsigned* counts= rowptr + NN;                   // M_ (pad to 200704)
  unsigned* bsums = counts + 200704;               // SBLK (pad 256)
  int* es         = (int*)(bsums + 256);           // ET
  float* alpha    = (float*)(es + ET);             // ET
  unsigned* gmax  = (unsigned*)(alpha + ET);       // NG*HID
  float* gsum     = (float*)(gmax + NG * HID);     // NG*HID
  unsigned* cnt   = (unsigned*)(gsum + NG * HID);  // NG
  // pairs staging aliases h/act (13.6MB <= 51.2MB); consumed before k_node1 writes h
  int2* pairs     = (int2*)h;

  // ---- CSR build via contention-free counting sort (topology shared) ----
  k_cnt  <<<NCH, 256, 0, stream>>>(ei, counts);
  k_scan1<<<SBLK, 256, 0, stream>>>(counts, bsums);
  k_scan2<<<1, 64, 0, stream>>>(bsums);
  k_scan3<<<SBLK, 256, 0, stream>>>(counts, bsums);
  k_place<<<NCH, 256, 0, stream>>>(ei, counts, pairs);
  k_bcsr <<<NBKT, 256, 0, stream>>>(pairs, counts, rowptr, deg, es);

  // ---- layer 1 ----
  k_node1<<<NN / 4, 256, 0, stream>>>(x, W1, as1, ad1, h, a_s, a_d);
  k_attn <<<NN / 4, 256, 0, stream>>>(es, rowptr, deg, a_s, a_d, alpha);
  k_wsum <<<NN / 4, 256, 0, stream>>>(es, alpha, rowptr, deg, h, b1, act);

  // ---- layer 2 ----
  k_node2<<<NN / 4, 256, 0, stream>>>(act, W2, as2, ad2, h, a_s, a_d);
  k_attn <<<NN / 4, 256, 0, stream>>>(es, rowptr, deg, a_s, a_d, alpha);
  k_wsum <<<NN / 4, 256, 0, stream>>>(es, alpha, rowptr, deg, h, b2, act);

  // ---- pooling + head ----
  hipMemsetAsync(gmax, 0, sizeof(unsigned) * NG * HID, stream);
  hipMemsetAsync(gsum, 0, sizeof(float) * NG * HID, stream);
  hipMemsetAsync(cnt,  0, sizeof(unsigned) * NG, stream);
  k_pool<<<(NN + 255) / 256, 256, 0, stream>>>(act, batch, gmax, gsum, cnt);
  k_final<<<NG / 4, 256, 0, stream>>>(gmax, gsum, cnt, fcw, fcb, out);
}

// Round 8
// 368.215 us; speedup vs baseline: 1.0052x; 1.0009x over previous
//
#include <hip/hip_runtime.h>
#include <hip/hip_fp16.h>

static constexpr int NN   = 100000;   // nodes
static constexpr int NE   = 1600000;  // edges (without self loops)
static constexpr int ET   = NE + NN;  // edges + self loops
static constexpr int NG   = 512;      // graphs
static constexpr int INF_ = 16;
static constexpr int HID  = 64;
static constexpr int BKT_SH = 7;                       // 128 nodes / bucket
static constexpr int NBKT = (NN + 127) / 128;          // 782 buckets
static constexpr int NCH  = 256;                       // edge chunks (counting sort)
static constexpr int CHUNK = (ET + NCH - 1) / NCH;     // 6641 edges / chunk
static constexpr int M_   = NBKT * NCH;                // counts matrix, 200192
static constexpr int SBLK = (M_ + 1023) / 1024;        // scan blocks (196)
#define NEG_SLOPE 0.2f

__device__ __forceinline__ float lrelu(float x) { return x > 0.f ? x : NEG_SLOPE * x; }

// accumulate 16 fp16 features (two 16B registers) into f32 accumulators
__device__ __forceinline__ void accum16(float* a, float al, float4 r0, float4 r1) {
  const __half2* p0 = (const __half2*)&r0;
  const __half2* p1 = (const __half2*)&r1;
#pragma unroll
  for (int j = 0; j < 4; ++j) {
    float2 f = __half22float2(p0[j]);
    a[2 * j]     += al * f.x;
    a[2 * j + 1] += al * f.y;
  }
#pragma unroll
  for (int j = 0; j < 4; ++j) {
    float2 f = __half22float2(p1[j]);
    a[8 + 2 * j]     += al * f.x;
    a[8 + 2 * j + 1] += al * f.y;
  }
}

// ---------- layer-1 node transform: h = relu(x) @ W1 (fp16 h out) ----------
__global__ __launch_bounds__(256) void k_node1(
    const float* __restrict__ x, const float* __restrict__ W,
    const float* __restrict__ atts, const float* __restrict__ attd,
    __half* __restrict__ h, float* __restrict__ a_s, float* __restrict__ a_d)
{
  __shared__ float Ws[INF_][HID];
  __shared__ float xs[4][INF_];
  const int tid = threadIdx.x;
  for (int i = tid; i < INF_ * HID; i += 256) Ws[i / HID][i % HID] = W[i];
  const int wv = tid >> 6, ln = tid & 63;
  const int n = blockIdx.x * 4 + wv;
  if (ln < INF_) {
    float v = x[n * INF_ + ln];
    xs[wv][ln] = v > 0.f ? v : 0.f;
  }
  __syncthreads();
  float acc = 0.f;
#pragma unroll
  for (int k = 0; k < INF_; ++k) acc += xs[wv][k] * Ws[k][ln];
  h[n * HID + ln] = __float2half(acc);
  float as = acc * atts[ln], ad = acc * attd[ln];
#pragma unroll
  for (int o = 32; o > 0; o >>= 1) { as += __shfl_xor(as, o); ad += __shfl_xor(ad, o); }
  if (ln == 0) { a_s[n] = as; a_d[n] = ad; }
}

// ---------- layer-2 node transform: h2 = act1 @ W2 (fp16 h out) ----------
__global__ __launch_bounds__(256) void k_node2(
    const float* __restrict__ act, const float* __restrict__ W,
    const float* __restrict__ atts, const float* __restrict__ attd,
    __half* __restrict__ h, float* __restrict__ a_s, float* __restrict__ a_d)
{
  __shared__ float Ws[HID][HID];   // 16 KB
  __shared__ float xs[4][HID];
  const int tid = threadIdx.x;
  for (int i = tid; i < HID * HID; i += 256) Ws[i / HID][i % HID] = W[i];
  const int wv = tid >> 6, ln = tid & 63;
  const int n = blockIdx.x * 4 + wv;
  xs[wv][ln] = act[n * HID + ln];
  __syncthreads();
  float acc = 0.f;
#pragma unroll
  for (int k = 0; k < HID; ++k) acc += xs[wv][k] * Ws[k][ln];
  h[n * HID + ln] = __float2half(acc);
  float as = acc * atts[ln], ad = acc * attd[ln];
#pragma unroll
  for (int o = 32; o > 0; o >>= 1) { as += __shfl_xor(as, o); ad += __shfl_xor(ad, o); }
  if (ln == 0) { a_s[n] = as; a_d[n] = ad; }
}

// ---------- counting sort pass A: per-chunk bucket histogram ----------
__global__ __launch_bounds__(256) void k_cnt(const int* __restrict__ ei,
                                             unsigned* __restrict__ counts)
{
  __shared__ unsigned lc[NBKT];
  for (int i = threadIdx.x; i < NBKT; i += 256) lc[i] = 0;
  __syncthreads();
  const int b = blockIdx.x;
  const int beg = b * CHUNK, end = min(ET, beg + CHUNK);
  for (int e = beg + threadIdx.x; e < end; e += 256) {
    int d = (e < NE) ? ei[NE + e] : e - NE;
    atomicAdd(&lc[d >> BKT_SH], 1u);
  }
  __syncthreads();
  for (int k = threadIdx.x; k < NBKT; k += 256) counts[k * NCH + b] = lc[k];
}

// ---------- scan pass 1: 1024-elem block sums over counts ----------
__global__ __launch_bounds__(256) void k_scan1(const unsigned* __restrict__ counts,
                                               unsigned* __restrict__ bsums)
{
  __shared__ unsigned red[4];
  const int t = threadIdx.x;
  const int base = blockIdx.x * 1024 + t * 4;
  unsigned s = 0;
#pragma unroll
  for (int k = 0; k < 4; ++k) { int i = base + k; if (i < M_) s += counts[i]; }
#pragma unroll
  for (int o = 32; o > 0; o >>= 1) s += __shfl_xor(s, o);
  if ((t & 63) == 0) red[t >> 6] = s;
  __syncthreads();
  if (t == 0) bsums[blockIdx.x] = red[0] + red[1] + red[2] + red[3];
}

// ---------- scan pass 2: exclusive scan of block sums (single wave) ----------
__global__ __launch_bounds__(64) void k_scan2(unsigned* __restrict__ bsums)
{
  const int ln = threadIdx.x;
  unsigned carry = 0;
  for (int base = 0; base < SBLK; base += 64) {
    int i = base + ln;
    unsigned orig = (i < SBLK) ? bsums[i] : 0;
    unsigned v = orig;
#pragma unroll
    for (int o = 1; o < 64; o <<= 1) { unsigned tv = __shfl_up(v, o); if (ln >= o) v += tv; }
    if (i < SBLK) bsums[i] = carry + v - orig;
    carry += __shfl(v, 63);
  }
}

// ---------- scan pass 3: add-back, exclusive scan in place ----------
__global__ __launch_bounds__(256) void k_scan3(unsigned* __restrict__ counts,
                                               const unsigned* __restrict__ bsums)
{
  __shared__ unsigned wsum[4];
  const int t = threadIdx.x;
  const int base = blockIdx.x * 1024 + t * 4;
  unsigned d[4]; unsigned s = 0;
#pragma unroll
  for (int k = 0; k < 4; ++k) { int i = base + k; d[k] = (i < M_) ? counts[i] : 0; s += d[k]; }
  unsigned v = s;
#pragma unroll
  for (int o = 1; o < 64; o <<= 1) { unsigned tv = __shfl_up(v, o); if ((t & 63) >= o) v += tv; }
  if ((t & 63) == 63) wsum[t >> 6] = v;
  __syncthreads();
  unsigned woff = 0;
  for (int w = 0; w < (t >> 6); ++w) woff += wsum[w];
  unsigned excl = woff + (v - s) + bsums[blockIdx.x];
#pragma unroll
  for (int k = 0; k < 4; ++k) {
    int i = base + k;
    if (i < M_) counts[i] = excl;
    excl += d[k];
  }
}

// ---------- counting sort pass C: place pairs (LDS cursors, no global atomics) ----------
__global__ __launch_bounds__(256) void k_place(const int* __restrict__ ei,
                                               const unsigned* __restrict__ S,
                                               int2* __restrict__ pairs)
{
  __shared__ unsigned cur[NBKT];
  const int b = blockIdx.x;
  for (int k = threadIdx.x; k < NBKT; k += 256) cur[k] = S[k * NCH + b];
  __syncthreads();
  const int beg = b * CHUNK, end = min(ET, beg + CHUNK);
  for (int e = beg + threadIdx.x; e < end; e += 256) {
    int s, d;
    if (e < NE) { s = ei[e]; d = ei[NE + e]; } else { s = d = e - NE; }
    unsigned pos = atomicAdd(&cur[d >> BKT_SH], 1u);
    pairs[pos] = make_int2(s, d);
  }
}

// ---------- per-bucket fine CSR build (reads scanned matrix directly) ----------
__global__ __launch_bounds__(256) void k_bcsr(const int2* __restrict__ pairs,
                                              const unsigned* __restrict__ S,
                                              unsigned* __restrict__ rowptr,
                                              unsigned* __restrict__ deg,
                                              int* __restrict__ es)
{
  __shared__ unsigned cnt[128], cur[128], wtot[2];
  const int b = blockIdx.x, t = threadIdx.x;
  const unsigned base = S[b * NCH];
  const unsigned m = ((b + 1 < NBKT) ? S[(b + 1) * NCH] : (unsigned)ET) - base;
  if (t < 128) cnt[t] = 0;
  __syncthreads();
  for (unsigned j = t; j < m; j += 256)
    atomicAdd(&cnt[pairs[base + j].y & 127], 1u);
  __syncthreads();
  unsigned c = 0, v = 0;
  if (t < 128) {
    c = cnt[t]; v = c;
    const int ln = t & 63;
#pragma unroll
    for (int o = 1; o < 64; o <<= 1) { unsigned tv = __shfl_up(v, o); if (ln >= o) v += tv; }
    if (ln == 63) wtot[t >> 6] = v;
  }
  __syncthreads();
  if (t < 128) {
    unsigned excl = v - c + ((t >= 64) ? wtot[0] : 0);
    cur[t] = excl;
    int node = (b << BKT_SH) + t;
    if (node < NN) { rowptr[node] = base + excl; deg[node] = c; }
  }
  __syncthreads();
  for (unsigned j = t; j < m; j += 256) {
    int2 p = pairs[base + j];
    unsigned pos = atomicAdd(&cur[p.y & 127], 1u);
    es[base + pos] = p.x;
  }
}

// ---------- attention: per-node max/den, write normalized alpha per edge ----------
__global__ __launch_bounds__(256) void k_attn(
    const int* __restrict__ es, const unsigned* __restrict__ rowptr,
    const unsigned* __restrict__ deg, const float* __restrict__ a_s,
    const float* __restrict__ a_d, float* __restrict__ alpha)
{
  const int wv = threadIdx.x >> 6, ln = threadIdx.x & 63;
  const int n = blockIdx.x * 4 + wv;
  const unsigned beg = rowptr[n], dg = deg[n];
  const float ad = a_d[n];
  const unsigned j0 = beg + (unsigned)ln;
  float l0 = -1e30f, m = -1e30f;
  if ((unsigned)ln < dg) { l0 = lrelu(a_s[es[j0]] + ad); m = l0; }
  for (unsigned j = beg + 64 + ln; j < beg + dg; j += 64)
    m = fmaxf(m, lrelu(a_s[es[j]] + ad));
#pragma unroll
  for (int o = 32; o > 0; o >>= 1) m = fmaxf(m, __shfl_xor(m, o));
  float ev0 = ((unsigned)ln < dg) ? __expf(l0 - m) : 0.f;
  float den = ev0;
  for (unsigned j = beg + 64 + ln; j < beg + dg; j += 64)
    den += __expf(lrelu(a_s[es[j]] + ad) - m);
#pragma unroll
  for (int o = 32; o > 0; o >>= 1) den += __shfl_xor(den, o);
  const float inv = 1.f / (den + 1e-16f);
  if ((unsigned)ln < dg) alpha[j0] = ev0 * inv;
  for (unsigned j = beg + 64 + ln; j < beg + dg; j += 64)
    alpha[j] = __expf(lrelu(a_s[es[j]] + ad) - m) * inv;
}

// ---------- weighted SpMM: wave per dst node, fp16 h rows (128B each) ----------
__global__ __launch_bounds__(256) void k_wsum(
    const int* __restrict__ es, const float* __restrict__ alpha,
    const unsigned* __restrict__ rowptr, const unsigned* __restrict__ deg,
    const __half* __restrict__ h, const float* __restrict__ bias,
    float* __restrict__ act)
{
  const int wv = threadIdx.x >> 6, ln = threadIdx.x & 63;
  const int n = blockIdx.x * 4 + wv;
  const unsigned beg = rowptr[n];
  const unsigned end = beg + deg[n];
  const int e16 = ln >> 2, q = ln & 3;
  float a[16];
#pragma unroll
  for (int k = 0; k < 16; ++k) a[k] = 0.f;

  for (unsigned c = beg; c < end; c += 32) {
    int s_st = 0; float al_st = 0.f;
    {
      unsigned j = c + (unsigned)ln;
      if (ln < 32 && j < end) { s_st = es[j]; al_st = alpha[j]; }
    }
    const int   sA  = __shfl(s_st, e16);
    const float alA = __shfl(al_st, e16);
    const int   sB  = __shfl(s_st, 16 + e16);
    const float alB = __shfl(al_st, 16 + e16);
    const bool vA = (c + (unsigned)e16) < end;
    const bool vB = (c + 16u + (unsigned)e16) < end;
    float4 a0, a1, b0, b1;
    if (vA) {
      const float4* hp = (const float4*)(h + (size_t)sA * HID + q * 16);
      a0 = hp[0]; a1 = hp[1];
    }
    if (vB) {
      const float4* hp = (const float4*)(h + (size_t)sB * HID + q * 16);
      b0 = hp[0]; b1 = hp[1];
    }
    if (vA) accum16(a, alA, a0, a1);
    if (vB) accum16(a, alB, b0, b1);
  }
  // reduce acc across the 16 edge-groups (strides 4..32)
#pragma unroll
  for (int o = 4; o < 64; o <<= 1) {
#pragma unroll
    for (int k = 0; k < 16; ++k) a[k] += __shfl_xor(a[k], o);
  }
  if (ln < 4) {   // lane ln holds features [ln*16, ln*16+16)
    float4* op = (float4*)(act + (size_t)n * HID + ln * 16);
    const float4* bp = (const float4*)(bias + ln * 16);
#pragma unroll
    for (int k = 0; k < 4; ++k) {
      float4 b4 = bp[k];
      float4 v;
      v.x = a[4 * k + 0] + b4.x;
      v.y = a[4 * k + 1] + b4.y;
      v.z = a[4 * k + 2] + b4.z;
      v.w = a[4 * k + 3] + b4.w;
      v.x = v.x > 0.f ? v.x : 0.f;
      v.y = v.y > 0.f ? v.y : 0.f;
      v.z = v.z > 0.f ? v.z : 0.f;
      v.w = v.w > 0.f ? v.w : 0.f;
      op[k] = v;
    }
  }
}

// ---------- pooling: per-graph max/sum over finalized act2 ----------
__global__ __launch_bounds__(256) void k_pool(
    const float* __restrict__ act, const int* __restrict__ batch,
    unsigned* __restrict__ gmax, float* __restrict__ gsum, unsigned* __restrict__ cnt)
{
  const int wv = threadIdx.x >> 6, ln = threadIdx.x & 63;
  const int base = (blockIdx.x * 4 + wv) * 64;
  if (base >= NN) return;
  const int end = min(NN, base + 64);
  float rmax = 0.f, rsum = 0.f;
  int cg = batch[base], run = 0;
  for (int n = base; n < end; ++n) {
    int g = batch[n];
    if (g != cg) {
      atomicMax(&gmax[cg * HID + ln], __float_as_uint(rmax));  // relu -> >=0
      unsafeAtomicAdd(&gsum[cg * HID + ln], rsum);
      if (ln == 0) atomicAdd(&cnt[cg], (unsigned)run);
      rmax = 0.f; rsum = 0.f; run = 0; cg = g;
    }
    float v = act[n * HID + ln];
    rmax = fmaxf(rmax, v); rsum += v; ++run;
  }
  atomicMax(&gmax[cg * HID + ln], __float_as_uint(rmax));
  unsafeAtomicAdd(&gsum[cg * HID + ln], rsum);
  if (ln == 0) atomicAdd(&cnt[cg], (unsigned)run);
}

// ---------- head: [gmax | gmean] @ fc_w + fc_b ----------
__global__ __launch_bounds__(256) void k_final(
    const unsigned* __restrict__ gmax, const float* __restrict__ gsum,
    const unsigned* __restrict__ cnt, const float* __restrict__ fcw,
    const float* __restrict__ fcb, float* __restrict__ out)
{
  const int wv = threadIdx.x >> 6, ln = threadIdx.x & 63;
  const int g = blockIdx.x * 4 + wv;
  if (g >= NG) return;
  float c = (float)cnt[g];
  float mx = __uint_as_float(gmax[g * HID + ln]);
  float mean = gsum[g * HID + ln] / fmaxf(c, 1.f);
  float v = mx * fcw[ln] + mean * fcw[HID + ln];
#pragma unroll
  for (int o = 32; o > 0; o >>= 1) v += __shfl_xor(v, o);
  if (ln == 0) out[g] = v + fcb[0];
}

extern "C" void kernel_launch(void* const* d_in, const int* in_sizes, int n_in,
                              void* d_out, int out_size, void* d_ws, size_t ws_size,
                              hipStream_t stream)
{
  const float* x    = (const float*)d_in[0];
  const int*   ei   = (const int*)d_in[1];
  const int*   batch= (const int*)d_in[2];
  const float* W1   = (const float*)d_in[3];
  const float* as1  = (const float*)d_in[4];
  const float* ad1  = (const float*)d_in[5];
  const float* b1   = (const float*)d_in[6];
  const float* W2   = (const float*)d_in[7];
  const float* as2  = (const float*)d_in[8];
  const float* ad2  = (const float*)d_in[9];
  const float* b2   = (const float*)d_in[10];
  const float* fcw  = (const float*)d_in[11];
  const float* fcb  = (const float*)d_in[12];
  float* out = (float*)d_out;

  __half* h       = (__half*)d_ws;                 // NN*HID halves (12.8MB)
  float* act      = (float*)(h + (size_t)NN * HID);// NN*HID f32 (25.6MB)
  float* a_s      = act + (size_t)NN * HID;        // NN
  float* a_d      = a_s + NN;                      // NN
  unsigned* deg   = (unsigned*)(a_d + NN);         // NN
  unsigned* rowptr= deg + NN;                      // NN
  unsigned* counts= rowptr + NN;                   // M_ (pad to 200704)
  unsigned* bsums = counts + 200704;               // SBLK (pad 256)
  int* es         = (int*)(bsums + 256);           // ET
  float* alpha    = (float*)(es + ET);             // ET
  unsigned* gmax  = (unsigned*)(alpha + ET);       // NG*HID
  float* gsum     = (float*)(gmax + NG * HID);     // NG*HID
  unsigned* cnt   = (unsigned*)(gsum + NG * HID);  // NG
  // pairs staging aliases act (13.6MB <= 25.6MB); consumed (k_bcsr) before
  // act is first written (k_wsum layer 1)
  int2* pairs     = (int2*)act;

  // ---- CSR build via contention-free counting sort (topology shared) ----
  k_cnt  <<<NCH, 256, 0, stream>>>(ei, counts);
  k_scan1<<<SBLK, 256, 0, stream>>>(counts, bsums);
  k_scan2<<<1, 64, 0, stream>>>(bsums);
  k_scan3<<<SBLK, 256, 0, stream>>>(counts, bsums);
  k_place<<<NCH, 256, 0, stream>>>(ei, counts, pairs);
  k_bcsr <<<NBKT, 256, 0, stream>>>(pairs, counts, rowptr, deg, es);

  // ---- layer 1 ----
  k_node1<<<NN / 4, 256, 0, stream>>>(x, W1, as1, ad1, h, a_s, a_d);
  k_attn <<<NN / 4, 256, 0, stream>>>(es, rowptr, deg, a_s, a_d, alpha);
  k_wsum <<<NN / 4, 256, 0, stream>>>(es, alpha, rowptr, deg, h, b1, act);

  // ---- layer 2 ----
  k_node2<<<NN / 4, 256, 0, stream>>>(act, W2, as2, ad2, h, a_s, a_d);
  k_attn <<<NN / 4, 256, 0, stream>>>(es, rowptr, deg, a_s, a_d, alpha);
  k_wsum <<<NN / 4, 256, 0, stream>>>(es, alpha, rowptr, deg, h, b2, act);

  // ---- pooling + head ----
  hipMemsetAsync(gmax, 0, sizeof(unsigned) * NG * HID, stream);
  hipMemsetAsync(gsum, 0, sizeof(float) * NG * HID, stream);
  hipMemsetAsync(cnt,  0, sizeof(unsigned) * NG, stream);
  k_pool<<<(NN + 255) / 256, 256, 0, stream>>>(act, batch, gmax, gsum, cnt);
  k_final<<<NG / 4, 256, 0, stream>>>(gmax, gsum, cnt, fcw, fcb, out);
}

// Round 9
// 341.922 us; speedup vs baseline: 1.0825x; 1.0769x over previous
//
#include <hip/hip_runtime.h>
#include <hip/hip_fp16.h>

static constexpr int NN   = 100000;   // nodes
static constexpr int NE   = 1600000;  // edges (without self loops)
static constexpr int ET   = NE + NN;  // edges + self loops
static constexpr int NG   = 512;      // graphs
static constexpr int INF_ = 16;
static constexpr int HID  = 64;
static constexpr int BKT_SH = 7;                       // 128 nodes / bucket
static constexpr int NBKT = (NN + 127) / 128;          // 782 buckets
static constexpr int NCH  = 256;                       // edge chunks (counting sort)
static constexpr int CHUNK = (ET + NCH - 1) / NCH;     // 6641 edges / chunk
static constexpr int M_   = NBKT * NCH;                // counts matrix, 200192
static constexpr int SBLK = (M_ + 1023) / 1024;        // scan blocks (196)
#define NEG_SLOPE 0.2f

__device__ __forceinline__ float lrelu(float x) { return x > 0.f ? x : NEG_SLOPE * x; }

// ---------- layer-1 node transform: h = relu(x) @ W1 (fp16 h out) ----------
__global__ __launch_bounds__(256) void k_node1(
    const float* __restrict__ x, const float* __restrict__ W,
    const float* __restrict__ atts, const float* __restrict__ attd,
    __half* __restrict__ h, float* __restrict__ a_s, float* __restrict__ a_d)
{
  __shared__ float Ws[INF_][HID];
  __shared__ float xs[4][INF_];
  const int tid = threadIdx.x;
  for (int i = tid; i < INF_ * HID; i += 256) Ws[i / HID][i % HID] = W[i];
  const int wv = tid >> 6, ln = tid & 63;
  const int n = blockIdx.x * 4 + wv;
  if (ln < INF_) {
    float v = x[n * INF_ + ln];
    xs[wv][ln] = v > 0.f ? v : 0.f;
  }
  __syncthreads();
  float acc = 0.f;
#pragma unroll
  for (int k = 0; k < INF_; ++k) acc += xs[wv][k] * Ws[k][ln];
  h[n * HID + ln] = __float2half(acc);
  float as = acc * atts[ln], ad = acc * attd[ln];
#pragma unroll
  for (int o = 32; o > 0; o >>= 1) { as += __shfl_xor(as, o); ad += __shfl_xor(ad, o); }
  if (ln == 0) { a_s[n] = as; a_d[n] = ad; }
}

// ---------- layer-2 node transform: h2 = act1 @ W2 (fp16 h out) ----------
__global__ __launch_bounds__(256) void k_node2(
    const float* __restrict__ act, const float* __restrict__ W,
    const float* __restrict__ atts, const float* __restrict__ attd,
    __half* __restrict__ h, float* __restrict__ a_s, float* __restrict__ a_d)
{
  __shared__ float Ws[HID][HID];   // 16 KB
  __shared__ float xs[4][HID];
  const int tid = threadIdx.x;
  for (int i = tid; i < HID * HID; i += 256) Ws[i / HID][i % HID] = W[i];
  const int wv = tid >> 6, ln = tid & 63;
  const int n = blockIdx.x * 4 + wv;
  xs[wv][ln] = act[n * HID + ln];
  __syncthreads();
  float acc = 0.f;
#pragma unroll
  for (int k = 0; k < HID; ++k) acc += xs[wv][k] * Ws[k][ln];
  h[n * HID + ln] = __float2half(acc);
  float as = acc * atts[ln], ad = acc * attd[ln];
#pragma unroll
  for (int o = 32; o > 0; o >>= 1) { as += __shfl_xor(as, o); ad += __shfl_xor(ad, o); }
  if (ln == 0) { a_s[n] = as; a_d[n] = ad; }
}

// ---------- counting sort pass A: per-chunk bucket histogram ----------
__global__ __launch_bounds__(256) void k_cnt(const int* __restrict__ ei,
                                             unsigned* __restrict__ counts)
{
  __shared__ unsigned lc[NBKT];
  for (int i = threadIdx.x; i < NBKT; i += 256) lc[i] = 0;
  __syncthreads();
  const int b = blockIdx.x;
  const int beg = b * CHUNK, end = min(ET, beg + CHUNK);
  for (int e = beg + threadIdx.x; e < end; e += 256) {
    int d = (e < NE) ? ei[NE + e] : e - NE;
    atomicAdd(&lc[d >> BKT_SH], 1u);
  }
  __syncthreads();
  for (int k = threadIdx.x; k < NBKT; k += 256) counts[k * NCH + b] = lc[k];
}

// ---------- scan pass 1: 1024-elem block sums over counts ----------
__global__ __launch_bounds__(256) void k_scan1(const unsigned* __restrict__ counts,
                                               unsigned* __restrict__ bsums)
{
  __shared__ unsigned red[4];
  const int t = threadIdx.x;
  const int base = blockIdx.x * 1024 + t * 4;
  unsigned s = 0;
#pragma unroll
  for (int k = 0; k < 4; ++k) { int i = base + k; if (i < M_) s += counts[i]; }
#pragma unroll
  for (int o = 32; o > 0; o >>= 1) s += __shfl_xor(s, o);
  if ((t & 63) == 0) red[t >> 6] = s;
  __syncthreads();
  if (t == 0) bsums[blockIdx.x] = red[0] + red[1] + red[2] + red[3];
}

// ---------- scan pass 2: exclusive scan of block sums (single wave) ----------
__global__ __launch_bounds__(64) void k_scan2(unsigned* __restrict__ bsums)
{
  const int ln = threadIdx.x;
  unsigned carry = 0;
  for (int base = 0; base < SBLK; base += 64) {
    int i = base + ln;
    unsigned orig = (i < SBLK) ? bsums[i] : 0;
    unsigned v = orig;
#pragma unroll
    for (int o = 1; o < 64; o <<= 1) { unsigned tv = __shfl_up(v, o); if (ln >= o) v += tv; }
    if (i < SBLK) bsums[i] = carry + v - orig;
    carry += __shfl(v, 63);
  }
}

// ---------- scan pass 3: add-back, exclusive scan in place ----------
__global__ __launch_bounds__(256) void k_scan3(unsigned* __restrict__ counts,
                                               const unsigned* __restrict__ bsums)
{
  __shared__ unsigned wsum[4];
  const int t = threadIdx.x;
  const int base = blockIdx.x * 1024 + t * 4;
  unsigned d[4]; unsigned s = 0;
#pragma unroll
  for (int k = 0; k < 4; ++k) { int i = base + k; d[k] = (i < M_) ? counts[i] : 0; s += d[k]; }
  unsigned v = s;
#pragma unroll
  for (int o = 1; o < 64; o <<= 1) { unsigned tv = __shfl_up(v, o); if ((t & 63) >= o) v += tv; }
  if ((t & 63) == 63) wsum[t >> 6] = v;
  __syncthreads();
  unsigned woff = 0;
  for (int w = 0; w < (t >> 6); ++w) woff += wsum[w];
  unsigned excl = woff + (v - s) + bsums[blockIdx.x];
#pragma unroll
  for (int k = 0; k < 4; ++k) {
    int i = base + k;
    if (i < M_) counts[i] = excl;
    excl += d[k];
  }
}

// ---------- counting sort pass C: place pairs (LDS cursors, no global atomics) ----------
__global__ __launch_bounds__(256) void k_place(const int* __restrict__ ei,
                                               const unsigned* __restrict__ S,
                                               int2* __restrict__ pairs)
{
  __shared__ unsigned cur[NBKT];
  const int b = blockIdx.x;
  for (int k = threadIdx.x; k < NBKT; k += 256) cur[k] = S[k * NCH + b];
  __syncthreads();
  const int beg = b * CHUNK, end = min(ET, beg + CHUNK);
  for (int e = beg + threadIdx.x; e < end; e += 256) {
    int s, d;
    if (e < NE) { s = ei[e]; d = ei[NE + e]; } else { s = d = e - NE; }
    unsigned pos = atomicAdd(&cur[d >> BKT_SH], 1u);
    pairs[pos] = make_int2(s, d);
  }
}

// ---------- per-bucket fine CSR build (reads scanned matrix directly) ----------
__global__ __launch_bounds__(256) void k_bcsr(const int2* __restrict__ pairs,
                                              const unsigned* __restrict__ S,
                                              unsigned* __restrict__ rowptr,
                                              unsigned* __restrict__ deg,
                                              int* __restrict__ es)
{
  __shared__ unsigned cnt[128], cur[128], wtot[2];
  const int b = blockIdx.x, t = threadIdx.x;
  const unsigned base = S[b * NCH];
  const unsigned m = ((b + 1 < NBKT) ? S[(b + 1) * NCH] : (unsigned)ET) - base;
  if (t < 128) cnt[t] = 0;
  __syncthreads();
  for (unsigned j = t; j < m; j += 256)
    atomicAdd(&cnt[pairs[base + j].y & 127], 1u);
  __syncthreads();
  unsigned c = 0, v = 0;
  if (t < 128) {
    c = cnt[t]; v = c;
    const int ln = t & 63;
#pragma unroll
    for (int o = 1; o < 64; o <<= 1) { unsigned tv = __shfl_up(v, o); if (ln >= o) v += tv; }
    if (ln == 63) wtot[t >> 6] = v;
  }
  __syncthreads();
  if (t < 128) {
    unsigned excl = v - c + ((t >= 64) ? wtot[0] : 0);
    cur[t] = excl;
    int node = (b << BKT_SH) + t;
    if (node < NN) { rowptr[node] = base + excl; deg[node] = c; }
  }
  __syncthreads();
  for (unsigned j = t; j < m; j += 256) {
    int2 p = pairs[base + j];
    unsigned pos = atomicAdd(&cur[p.y & 127], 1u);
    es[base + pos] = p.x;
  }
}

// ---------- attention: per-node max/den, write normalized alpha per edge ----------
__global__ __launch_bounds__(256) void k_attn(
    const int* __restrict__ es, const unsigned* __restrict__ rowptr,
    const unsigned* __restrict__ deg, const float* __restrict__ a_s,
    const float* __restrict__ a_d, float* __restrict__ alpha)
{
  const int wv = threadIdx.x >> 6, ln = threadIdx.x & 63;
  const int n = blockIdx.x * 4 + wv;
  const unsigned beg = rowptr[n], dg = deg[n];
  const float ad = a_d[n];
  const unsigned j0 = beg + (unsigned)ln;
  float l0 = -1e30f, m = -1e30f;
  if ((unsigned)ln < dg) { l0 = lrelu(a_s[es[j0]] + ad); m = l0; }
  for (unsigned j = beg + 64 + ln; j < beg + dg; j += 64)
    m = fmaxf(m, lrelu(a_s[es[j]] + ad));
#pragma unroll
  for (int o = 32; o > 0; o >>= 1) m = fmaxf(m, __shfl_xor(m, o));
  float ev0 = ((unsigned)ln < dg) ? __expf(l0 - m) : 0.f;
  float den = ev0;
  for (unsigned j = beg + 64 + ln; j < beg + dg; j += 64)
    den += __expf(lrelu(a_s[es[j]] + ad) - m);
#pragma unroll
  for (int o = 32; o > 0; o >>= 1) den += __shfl_xor(den, o);
  const float inv = 1.f / (den + 1e-16f);
  if ((unsigned)ln < dg) alpha[j0] = ev0 * inv;
  for (unsigned j = beg + 64 + ln; j < beg + dg; j += 64)
    alpha[j] = __expf(lrelu(a_s[es[j]] + ad) - m) * inv;
}

// ---------- weighted SpMM: wave per node, lane-owns-feature, ZERO cross-lane ----------
// lane ln accumulates feature ln; edge meta (es/alpha) via wave-uniform scalar
// loads (readfirstlane'd indices); 16 independent coalesced 128B row loads in
// flight per wave; no shuffle epilogue (DS unit untouched).
__global__ __launch_bounds__(256) void k_wsum(
    const int* __restrict__ es, const float* __restrict__ alpha,
    const unsigned* __restrict__ rowptr, const unsigned* __restrict__ deg,
    const __half* __restrict__ h, const float* __restrict__ bias,
    float* __restrict__ act)
{
  const int wv = threadIdx.x >> 6, ln = threadIdx.x & 63;
  const int n = blockIdx.x * 4 + wv;
  const unsigned beg  = (unsigned)__builtin_amdgcn_readfirstlane((int)rowptr[n]);
  const unsigned dg   = (unsigned)__builtin_amdgcn_readfirstlane((int)deg[n]);
  const unsigned end  = beg + dg;
  const unsigned last = end - 1;           // deg >= 1 (self loop)
  float acc = 0.f;
  for (unsigned j = beg; j < end; j += 16) {
    int s[16]; float al[16]; __half hv[16];
#pragma unroll
    for (int k = 0; k < 16; ++k) {
      unsigned jj = j + (unsigned)k;
      unsigned jc = jj < last ? jj : last;   // uniform clamp
      s[k]  = es[jc];
      al[k] = (jj < end) ? alpha[jc] : 0.f;
    }
#pragma unroll
    for (int k = 0; k < 16; ++k) hv[k] = h[(size_t)s[k] * HID + ln];
#pragma unroll
    for (int k = 0; k < 16; ++k) acc += al[k] * __half2float(hv[k]);
  }
  float v = acc + bias[ln];
  act[(size_t)n * HID + ln] = v > 0.f ? v : 0.f;
}

// ---------- pooling: per-graph max/sum over finalized act2 ----------
__global__ __launch_bounds__(256) void k_pool(
    const float* __restrict__ act, const int* __restrict__ batch,
    unsigned* __restrict__ gmax, float* __restrict__ gsum, unsigned* __restrict__ cnt)
{
  const int wv = threadIdx.x >> 6, ln = threadIdx.x & 63;
  const int base = (blockIdx.x * 4 + wv) * 64;
  if (base >= NN) return;
  const int end = min(NN, base + 64);
  float rmax = 0.f, rsum = 0.f;
  int cg = batch[base], run = 0;
  for (int n = base; n < end; ++n) {
    int g = batch[n];
    if (g != cg) {
      atomicMax(&gmax[cg * HID + ln], __float_as_uint(rmax));  // relu -> >=0
      unsafeAtomicAdd(&gsum[cg * HID + ln], rsum);
      if (ln == 0) atomicAdd(&cnt[cg], (unsigned)run);
      rmax = 0.f; rsum = 0.f; run = 0; cg = g;
    }
    float v = act[n * HID + ln];
    rmax = fmaxf(rmax, v); rsum += v; ++run;
  }
  atomicMax(&gmax[cg * HID + ln], __float_as_uint(rmax));
  unsafeAtomicAdd(&gsum[cg * HID + ln], rsum);
  if (ln == 0) atomicAdd(&cnt[cg], (unsigned)run);
}

// ---------- head: [gmax | gmean] @ fc_w + fc_b ----------
__global__ __launch_bounds__(256) void k_final(
    const unsigned* __restrict__ gmax, const float* __restrict__ gsum,
    const unsigned* __restrict__ cnt, const float* __restrict__ fcw,
    const float* __restrict__ fcb, float* __restrict__ out)
{
  const int wv = threadIdx.x >> 6, ln = threadIdx.x & 63;
  const int g = blockIdx.x * 4 + wv;
  if (g >= NG) return;
  float c = (float)cnt[g];
  float mx = __uint_as_float(gmax[g * HID + ln]);
  float mean = gsum[g * HID + ln] / fmaxf(c, 1.f);
  float v = mx * fcw[ln] + mean * fcw[HID + ln];
#pragma unroll
  for (int o = 32; o > 0; o >>= 1) v += __shfl_xor(v, o);
  if (ln == 0) out[g] = v + fcb[0];
}

extern "C" void kernel_launch(void* const* d_in, const int* in_sizes, int n_in,
                              void* d_out, int out_size, void* d_ws, size_t ws_size,
                              hipStream_t stream)
{
  const float* x    = (const float*)d_in[0];
  const int*   ei   = (const int*)d_in[1];
  const int*   batch= (const int*)d_in[2];
  const float* W1   = (const float*)d_in[3];
  const float* as1  = (const float*)d_in[4];
  const float* ad1  = (const float*)d_in[5];
  const float* b1   = (const float*)d_in[6];
  const float* W2   = (const float*)d_in[7];
  const float* as2  = (const float*)d_in[8];
  const float* ad2  = (const float*)d_in[9];
  const float* b2   = (const float*)d_in[10];
  const float* fcw  = (const float*)d_in[11];
  const float* fcb  = (const float*)d_in[12];
  float* out = (float*)d_out;

  __half* h       = (__half*)d_ws;                 // NN*HID halves (12.8MB)
  float* act      = (float*)(h + (size_t)NN * HID);// NN*HID f32 (25.6MB)
  float* a_s      = act + (size_t)NN * HID;        // NN
  float* a_d      = a_s + NN;                      // NN
  unsigned* deg   = (unsigned*)(a_d + NN);         // NN
  unsigned* rowptr= deg + NN;                      // NN
  unsigned* counts= rowptr + NN;                   // M_ (pad to 200704)
  unsigned* bsums = counts + 200704;               // SBLK (pad 256)
  int* es         = (int*)(bsums + 256);           // ET
  float* alpha    = (float*)(es + ET);             // ET
  unsigned* gmax  = (unsigned*)(alpha + ET);       // NG*HID
  float* gsum     = (float*)(gmax + NG * HID);     // NG*HID
  unsigned* cnt   = (unsigned*)(gsum + NG * HID);  // NG
  // pairs staging aliases act (13.6MB <= 25.6MB); consumed (k_bcsr) before
  // act is first written (k_wsum layer 1)
  int2* pairs     = (int2*)act;

  // ---- CSR build via contention-free counting sort (topology shared) ----
  k_cnt  <<<NCH, 256, 0, stream>>>(ei, counts);
  k_scan1<<<SBLK, 256, 0, stream>>>(counts, bsums);
  k_scan2<<<1, 64, 0, stream>>>(bsums);
  k_scan3<<<SBLK, 256, 0, stream>>>(counts, bsums);
  k_place<<<NCH, 256, 0, stream>>>(ei, counts, pairs);
  k_bcsr <<<NBKT, 256, 0, stream>>>(pairs, counts, rowptr, deg, es);

  // ---- layer 1 ----
  k_node1<<<NN / 4, 256, 0, stream>>>(x, W1, as1, ad1, h, a_s, a_d);
  k_attn <<<NN / 4, 256, 0, stream>>>(es, rowptr, deg, a_s, a_d, alpha);
  k_wsum <<<NN / 4, 256, 0, stream>>>(es, alpha, rowptr, deg, h, b1, act);

  // ---- layer 2 ----
  k_node2<<<NN / 4, 256, 0, stream>>>(act, W2, as2, ad2, h, a_s, a_d);
  k_attn <<<NN / 4, 256, 0, stream>>>(es, rowptr, deg, a_s, a_d, alpha);
  k_wsum <<<NN / 4, 256, 0, stream>>>(es, alpha, rowptr, deg, h, b2, act);

  // ---- pooling + head ----
  hipMemsetAsync(gmax, 0, sizeof(unsigned) * NG * HID, stream);
  hipMemsetAsync(gsum, 0, sizeof(float) * NG * HID, stream);
  hipMemsetAsync(cnt,  0, sizeof(unsigned) * NG, stream);
  k_pool<<<(NN + 255) / 256, 256, 0, stream>>>(act, batch, gmax, gsum, cnt);
  k_final<<<NG / 4, 256, 0, stream>>>(gmax, gsum, cnt, fcw, fcb, out);
}

// Round 10
// 267.283 us; speedup vs baseline: 1.3848x; 1.2793x over previous
//
#include <hip/hip_runtime.h>
#include <hip/hip_fp16.h>

static constexpr int NN   = 100000;   // nodes
static constexpr int NE   = 1600000;  // edges (without self loops)
static constexpr int ET   = NE + NN;  // edges + self loops
static constexpr int NG   = 512;      // graphs
static constexpr int INF_ = 16;
static constexpr int HID  = 64;
static constexpr int BKT_SH = 7;                       // 128 nodes / bucket
static constexpr int NBKT = (NN + 127) / 128;          // 782 buckets
static constexpr int NCH  = 256;                       // edge chunks (counting sort)
static constexpr int CHUNK = (ET + NCH - 1) / NCH;     // 6641 edges / chunk
static constexpr int M_   = NBKT * NCH;                // counts matrix, 200192
static constexpr int SBLK = (M_ + 1023) / 1024;        // scan blocks (196)
#define NEG_SLOPE 0.2f

typedef _Float16 f16x8 __attribute__((ext_vector_type(8)));
typedef float    f32x4 __attribute__((ext_vector_type(4)));

__device__ __forceinline__ float lrelu(float x) { return x > 0.f ? x : NEG_SLOPE * x; }

// ---------- layer-1 node transform via MFMA: h = relu(x) @ W1 (fp16 h out) ----------
// wave computes 16 nodes x 64 cols; hi/lo fp16 split reconstructs f32 GEMM.
__global__ __launch_bounds__(256) void k_node1(
    const float* __restrict__ x, const float* __restrict__ W,
    const float* __restrict__ atts, const float* __restrict__ attd,
    __half* __restrict__ h, float* __restrict__ a_s, float* __restrict__ a_d)
{
  const int wv = threadIdx.x >> 6, ln = threadIdx.x & 63;
  const int lr = ln & 15, lk = ln >> 4;
  // B frags (K=16 padded to 32): [ct] hi/lo
  f16x8 Bh[4], Bl[4];
#pragma unroll
  for (int ct = 0; ct < 4; ++ct) {
    f16x8 bh = {}, bl = {};
    if (lk < 2) {
#pragma unroll
      for (int j = 0; j < 8; ++j) {
        float w = W[(lk * 8 + j) * HID + ct * 16 + lr];
        _Float16 hh = (_Float16)w;
        bh[j] = hh; bl[j] = (_Float16)(w - (float)hh);
      }
    }
    Bh[ct] = bh; Bl[ct] = bl;
  }
  const int NT = NN / 16;
  for (int nt = blockIdx.x * 4 + wv; nt < NT; nt += gridDim.x * 4) {
    const int nbase = nt * 16;
    f16x8 Ah = {}, Al = {};
    if (lk < 2) {
      const float* xr = x + (size_t)(nbase + lr) * INF_ + lk * 8;
#pragma unroll
      for (int j = 0; j < 8; ++j) {
        float v = xr[j]; v = v > 0.f ? v : 0.f;
        _Float16 hh = (_Float16)v;
        Ah[j] = hh; Al[j] = (_Float16)(v - (float)hh);
      }
    }
    f32x4 C[4];
#pragma unroll
    for (int ct = 0; ct < 4; ++ct) {
      f32x4 c = {0.f, 0.f, 0.f, 0.f};
      c = __builtin_amdgcn_mfma_f32_16x16x32_f16(Ah, Bh[ct], c, 0, 0, 0);
      c = __builtin_amdgcn_mfma_f32_16x16x32_f16(Ah, Bl[ct], c, 0, 0, 0);
      c = __builtin_amdgcn_mfma_f32_16x16x32_f16(Al, Bh[ct], c, 0, 0, 0);
      C[ct] = c;
    }
    float asp[4] = {0.f, 0.f, 0.f, 0.f}, adp[4] = {0.f, 0.f, 0.f, 0.f};
#pragma unroll
    for (int ct = 0; ct < 4; ++ct) {
      float at_s = atts[ct * 16 + lr], at_d = attd[ct * 16 + lr];
#pragma unroll
      for (int r = 0; r < 4; ++r) {
        float v = C[ct][r];
        h[(size_t)(nbase + lk * 4 + r) * HID + ct * 16 + lr] = __float2half(v);
        asp[r] += v * at_s; adp[r] += v * at_d;
      }
    }
#pragma unroll
    for (int o = 1; o < 16; o <<= 1) {
#pragma unroll
      for (int r = 0; r < 4; ++r) {
        asp[r] += __shfl_xor(asp[r], o);
        adp[r] += __shfl_xor(adp[r], o);
      }
    }
    if (lr == 0) {
#pragma unroll
      for (int r = 0; r < 4; ++r) {
        a_s[nbase + lk * 4 + r] = asp[r];
        a_d[nbase + lk * 4 + r] = adp[r];
      }
    }
  }
}

// ---------- layer-2 node transform via MFMA: h2 = act1 @ W2 (fp16 h out) ----------
__global__ __launch_bounds__(256) void k_node2(
    const float* __restrict__ act, const float* __restrict__ W,
    const float* __restrict__ atts, const float* __restrict__ attd,
    __half* __restrict__ h, float* __restrict__ a_s, float* __restrict__ a_d)
{
  const int wv = threadIdx.x >> 6, ln = threadIdx.x & 63;
  const int lr = ln & 15, lk = ln >> 4;
  // B frags: [ct][kslice] hi/lo, loaded once (W2 is 16KB, L2-resident)
  f16x8 Bh[4][2], Bl[4][2];
#pragma unroll
  for (int ct = 0; ct < 4; ++ct)
#pragma unroll
    for (int ks = 0; ks < 2; ++ks) {
      f16x8 bh, bl;
#pragma unroll
      for (int j = 0; j < 8; ++j) {
        float w = W[(ks * 32 + lk * 8 + j) * HID + ct * 16 + lr];
        _Float16 hh = (_Float16)w;
        bh[j] = hh; bl[j] = (_Float16)(w - (float)hh);
      }
      Bh[ct][ks] = bh; Bl[ct][ks] = bl;
    }
  const int NT = NN / 16;
  for (int nt = blockIdx.x * 4 + wv; nt < NT; nt += gridDim.x * 4) {
    const int nbase = nt * 16;
    const float* ar = act + (size_t)(nbase + lr) * HID + lk * 8;
    f16x8 A0h, A0l, A1h, A1l;
#pragma unroll
    for (int j = 0; j < 8; ++j) {
      float v = ar[j];
      _Float16 hh = (_Float16)v;
      A0h[j] = hh; A0l[j] = (_Float16)(v - (float)hh);
    }
#pragma unroll
    for (int j = 0; j < 8; ++j) {
      float v = ar[32 + j];
      _Float16 hh = (_Float16)v;
      A1h[j] = hh; A1l[j] = (_Float16)(v - (float)hh);
    }
    f32x4 C[4];
#pragma unroll
    for (int ct = 0; ct < 4; ++ct) {
      f32x4 c = {0.f, 0.f, 0.f, 0.f};
      c = __builtin_amdgcn_mfma_f32_16x16x32_f16(A0h, Bh[ct][0], c, 0, 0, 0);
      c = __builtin_amdgcn_mfma_f32_16x16x32_f16(A0h, Bl[ct][0], c, 0, 0, 0);
      c = __builtin_amdgcn_mfma_f32_16x16x32_f16(A0l, Bh[ct][0], c, 0, 0, 0);
      c = __builtin_amdgcn_mfma_f32_16x16x32_f16(A1h, Bh[ct][1], c, 0, 0, 0);
      c = __builtin_amdgcn_mfma_f32_16x16x32_f16(A1h, Bl[ct][1], c, 0, 0, 0);
      c = __builtin_amdgcn_mfma_f32_16x16x32_f16(A1l, Bh[ct][1], c, 0, 0, 0);
      C[ct] = c;
    }
    float asp[4] = {0.f, 0.f, 0.f, 0.f}, adp[4] = {0.f, 0.f, 0.f, 0.f};
#pragma unroll
    for (int ct = 0; ct < 4; ++ct) {
      float at_s = atts[ct * 16 + lr], at_d = attd[ct * 16 + lr];
#pragma unroll
      for (int r = 0; r < 4; ++r) {
        float v = C[ct][r];
        h[(size_t)(nbase + lk * 4 + r) * HID + ct * 16 + lr] = __float2half(v);
        asp[r] += v * at_s; adp[r] += v * at_d;
      }
    }
#pragma unroll
    for (int o = 1; o < 16; o <<= 1) {
#pragma unroll
      for (int r = 0; r < 4; ++r) {
        asp[r] += __shfl_xor(asp[r], o);
        adp[r] += __shfl_xor(adp[r], o);
      }
    }
    if (lr == 0) {
#pragma unroll
      for (int r = 0; r < 4; ++r) {
        a_s[nbase + lk * 4 + r] = asp[r];
        a_d[nbase + lk * 4 + r] = adp[r];
      }
    }
  }
}

// ---------- counting sort pass A: per-chunk bucket histogram ----------
__global__ __launch_bounds__(256) void k_cnt(const int* __restrict__ ei,
                                             unsigned* __restrict__ counts)
{
  __shared__ unsigned lc[NBKT];
  for (int i = threadIdx.x; i < NBKT; i += 256) lc[i] = 0;
  __syncthreads();
  const int b = blockIdx.x;
  const int beg = b * CHUNK, end = min(ET, beg + CHUNK);
  for (int e = beg + threadIdx.x; e < end; e += 256) {
    int d = (e < NE) ? ei[NE + e] : e - NE;
    atomicAdd(&lc[d >> BKT_SH], 1u);
  }
  __syncthreads();
  for (int k = threadIdx.x; k < NBKT; k += 256) counts[k * NCH + b] = lc[k];
}

// ---------- scan pass 1: 1024-elem block sums over counts ----------
__global__ __launch_bounds__(256) void k_scan1(const unsigned* __restrict__ counts,
                                               unsigned* __restrict__ bsums)
{
  __shared__ unsigned red[4];
  const int t = threadIdx.x;
  const int base = blockIdx.x * 1024 + t * 4;
  unsigned s = 0;
#pragma unroll
  for (int k = 0; k < 4; ++k) { int i = base + k; if (i < M_) s += counts[i]; }
#pragma unroll
  for (int o = 32; o > 0; o >>= 1) s += __shfl_xor(s, o);
  if ((t & 63) == 0) red[t >> 6] = s;
  __syncthreads();
  if (t == 0) bsums[blockIdx.x] = red[0] + red[1] + red[2] + red[3];
}

// ---------- scan pass 2: exclusive scan of block sums (single wave) ----------
__global__ __launch_bounds__(64) void k_scan2(unsigned* __restrict__ bsums)
{
  const int ln = threadIdx.x;
  unsigned carry = 0;
  for (int base = 0; base < SBLK; base += 64) {
    int i = base + ln;
    unsigned orig = (i < SBLK) ? bsums[i] : 0;
    unsigned v = orig;
#pragma unroll
    for (int o = 1; o < 64; o <<= 1) { unsigned tv = __shfl_up(v, o); if (ln >= o) v += tv; }
    if (i < SBLK) bsums[i] = carry + v - orig;
    carry += __shfl(v, 63);
  }
}

// ---------- scan pass 3: add-back, exclusive scan in place ----------
__global__ __launch_bounds__(256) void k_scan3(unsigned* __restrict__ counts,
                                               const unsigned* __restrict__ bsums)
{
  __shared__ unsigned wsum[4];
  const int t = threadIdx.x;
  const int base = blockIdx.x * 1024 + t * 4;
  unsigned d[4]; unsigned s = 0;
#pragma unroll
  for (int k = 0; k < 4; ++k) { int i = base + k; d[k] = (i < M_) ? counts[i] : 0; s += d[k]; }
  unsigned v = s;
#pragma unroll
  for (int o = 1; o < 64; o <<= 1) { unsigned tv = __shfl_up(v, o); if ((t & 63) >= o) v += tv; }
  if ((t & 63) == 63) wsum[t >> 6] = v;
  __syncthreads();
  unsigned woff = 0;
  for (int w = 0; w < (t >> 6); ++w) woff += wsum[w];
  unsigned excl = woff + (v - s) + bsums[blockIdx.x];
#pragma unroll
  for (int k = 0; k < 4; ++k) {
    int i = base + k;
    if (i < M_) counts[i] = excl;
    excl += d[k];
  }
}

// ---------- counting sort pass C: place pairs (LDS cursors, no global atomics) ----------
__global__ __launch_bounds__(256) void k_place(const int* __restrict__ ei,
                                               const unsigned* __restrict__ S,
                                               int2* __restrict__ pairs)
{
  __shared__ unsigned cur[NBKT];
  const int b = blockIdx.x;
  for (int k = threadIdx.x; k < NBKT; k += 256) cur[k] = S[k * NCH + b];
  __syncthreads();
  const int beg = b * CHUNK, end = min(ET, beg + CHUNK);
  for (int e = beg + threadIdx.x; e < end; e += 256) {
    int s, d;
    if (e < NE) { s = ei[e]; d = ei[NE + e]; } else { s = d = e - NE; }
    unsigned pos = atomicAdd(&cur[d >> BKT_SH], 1u);
    pairs[pos] = make_int2(s, d);
  }
}

// ---------- per-bucket fine CSR build (reads scanned matrix directly) ----------
__global__ __launch_bounds__(256) void k_bcsr(const int2* __restrict__ pairs,
                                              const unsigned* __restrict__ S,
                                              unsigned* __restrict__ rowptr,
                                              unsigned* __restrict__ deg,
                                              int* __restrict__ es)
{
  __shared__ unsigned cnt[128], cur[128], wtot[2];
  const int b = blockIdx.x, t = threadIdx.x;
  const unsigned base = S[b * NCH];
  const unsigned m = ((b + 1 < NBKT) ? S[(b + 1) * NCH] : (unsigned)ET) - base;
  if (t < 128) cnt[t] = 0;
  __syncthreads();
  for (unsigned j = t; j < m; j += 256)
    atomicAdd(&cnt[pairs[base + j].y & 127], 1u);
  __syncthreads();
  unsigned c = 0, v = 0;
  if (t < 128) {
    c = cnt[t]; v = c;
    const int ln = t & 63;
#pragma unroll
    for (int o = 1; o < 64; o <<= 1) { unsigned tv = __shfl_up(v, o); if (ln >= o) v += tv; }
    if (ln == 63) wtot[t >> 6] = v;
  }
  __syncthreads();
  if (t < 128) {
    unsigned excl = v - c + ((t >= 64) ? wtot[0] : 0);
    cur[t] = excl;
    int node = (b << BKT_SH) + t;
    if (node < NN) { rowptr[node] = base + excl; deg[node] = c; }
  }
  __syncthreads();
  for (unsigned j = t; j < m; j += 256) {
    int2 p = pairs[base + j];
    unsigned pos = atomicAdd(&cur[p.y & 127], 1u);
    es[base + pos] = p.x;
  }
}

// ---------- attention: per-node max/den, write normalized alpha per edge ----------
__global__ __launch_bounds__(256) void k_attn(
    const int* __restrict__ es, const unsigned* __restrict__ rowptr,
    const unsigned* __restrict__ deg, const float* __restrict__ a_s,
    const float* __restrict__ a_d, float* __restrict__ alpha)
{
  const int wv = threadIdx.x >> 6, ln = threadIdx.x & 63;
  const int n = blockIdx.x * 4 + wv;
  const unsigned beg = rowptr[n], dg = deg[n];
  const float ad = a_d[n];
  const unsigned j0 = beg + (unsigned)ln;
  float l0 = -1e30f, m = -1e30f;
  if ((unsigned)ln < dg) { l0 = lrelu(a_s[es[j0]] + ad); m = l0; }
  for (unsigned j = beg + 64 + ln; j < beg + dg; j += 64)
    m = fmaxf(m, lrelu(a_s[es[j]] + ad));
#pragma unroll
  for (int o = 32; o > 0; o >>= 1) m = fmaxf(m, __shfl_xor(m, o));
  float ev0 = ((unsigned)ln < dg) ? __expf(l0 - m) : 0.f;
  float den = ev0;
  for (unsigned j = beg + 64 + ln; j < beg + dg; j += 64)
    den += __expf(lrelu(a_s[es[j]] + ad) - m);
#pragma unroll
  for (int o = 32; o > 0; o >>= 1) den += __shfl_xor(den, o);
  const float inv = 1.f / (den + 1e-16f);
  if ((unsigned)ln < dg) alpha[j0] = ev0 * inv;
  for (unsigned j = beg + 64 + ln; j < beg + dg; j += 64)
    alpha[j] = __expf(lrelu(a_s[es[j]] + ad) - m) * inv;
}

// ---------- weighted SpMM: wave per node, lane-owns-feature, ZERO cross-lane ----------
__global__ __launch_bounds__(256) void k_wsum(
    const int* __restrict__ es, const float* __restrict__ alpha,
    const unsigned* __restrict__ rowptr, const unsigned* __restrict__ deg,
    const __half* __restrict__ h, const float* __restrict__ bias,
    float* __restrict__ act)
{
  const int wv = threadIdx.x >> 6, ln = threadIdx.x & 63;
  const int n = blockIdx.x * 4 + wv;
  const unsigned beg  = (unsigned)__builtin_amdgcn_readfirstlane((int)rowptr[n]);
  const unsigned dg   = (unsigned)__builtin_amdgcn_readfirstlane((int)deg[n]);
  const unsigned end  = beg + dg;
  const unsigned last = end - 1;           // deg >= 1 (self loop)
  float acc = 0.f;
  for (unsigned j = beg; j < end; j += 16) {
    int s[16]; float al[16]; __half hv[16];
#pragma unroll
    for (int k = 0; k < 16; ++k) {
      unsigned jj = j + (unsigned)k;
      unsigned jc = jj < last ? jj : last;   // uniform clamp
      s[k]  = es[jc];
      al[k] = (jj < end) ? alpha[jc] : 0.f;
    }
#pragma unroll
    for (int k = 0; k < 16; ++k) hv[k] = h[(size_t)s[k] * HID + ln];
#pragma unroll
    for (int k = 0; k < 16; ++k) acc += al[k] * __half2float(hv[k]);
  }
  float v = acc + bias[ln];
  act[(size_t)n * HID + ln] = v > 0.f ? v : 0.f;
}

// ---------- pooling: per-graph max/sum over finalized act2 ----------
__global__ __launch_bounds__(256) void k_pool(
    const float* __restrict__ act, const int* __restrict__ batch,
    unsigned* __restrict__ gmax, float* __restrict__ gsum, unsigned* __restrict__ cnt)
{
  const int wv = threadIdx.x >> 6, ln = threadIdx.x & 63;
  const int base = (blockIdx.x * 4 + wv) * 64;
  if (base >= NN) return;
  const int end = min(NN, base + 64);
  float rmax = 0.f, rsum = 0.f;
  int cg = batch[base], run = 0;
  for (int n = base; n < end; ++n) {
    int g = batch[n];
    if (g != cg) {
      atomicMax(&gmax[cg * HID + ln], __float_as_uint(rmax));  // relu -> >=0
      unsafeAtomicAdd(&gsum[cg * HID + ln], rsum);
      if (ln == 0) atomicAdd(&cnt[cg], (unsigned)run);
      rmax = 0.f; rsum = 0.f; run = 0; cg = g;
    }
    float v = act[n * HID + ln];
    rmax = fmaxf(rmax, v); rsum += v; ++run;
  }
  atomicMax(&gmax[cg * HID + ln], __float_as_uint(rmax));
  unsafeAtomicAdd(&gsum[cg * HID + ln], rsum);
  if (ln == 0) atomicAdd(&cnt[cg], (unsigned)run);
}

// ---------- head: [gmax | gmean] @ fc_w + fc_b ----------
__global__ __launch_bounds__(256) void k_final(
    const unsigned* __restrict__ gmax, const float* __restrict__ gsum,
    const unsigned* __restrict__ cnt, const float* __restrict__ fcw,
    const float* __restrict__ fcb, float* __restrict__ out)
{
  const int wv = threadIdx.x >> 6, ln = threadIdx.x & 63;
  const int g = blockIdx.x * 4 + wv;
  if (g >= NG) return;
  float c = (float)cnt[g];
  float mx = __uint_as_float(gmax[g * HID + ln]);
  float mean = gsum[g * HID + ln] / fmaxf(c, 1.f);
  float v = mx * fcw[ln] + mean * fcw[HID + ln];
#pragma unroll
  for (int o = 32; o > 0; o >>= 1) v += __shfl_xor(v, o);
  if (ln == 0) out[g] = v + fcb[0];
}

extern "C" void kernel_launch(void* const* d_in, const int* in_sizes, int n_in,
                              void* d_out, int out_size, void* d_ws, size_t ws_size,
                              hipStream_t stream)
{
  const float* x    = (const float*)d_in[0];
  const int*   ei   = (const int*)d_in[1];
  const int*   batch= (const int*)d_in[2];
  const float* W1   = (const float*)d_in[3];
  const float* as1  = (const float*)d_in[4];
  const float* ad1  = (const float*)d_in[5];
  const float* b1   = (const float*)d_in[6];
  const float* W2   = (const float*)d_in[7];
  const float* as2  = (const float*)d_in[8];
  const float* ad2  = (const float*)d_in[9];
  const float* b2   = (const float*)d_in[10];
  const float* fcw  = (const float*)d_in[11];
  const float* fcb  = (const float*)d_in[12];
  float* out = (float*)d_out;

  __half* h       = (__half*)d_ws;                 // NN*HID halves (12.8MB)
  float* act      = (float*)(h + (size_t)NN * HID);// NN*HID f32 (25.6MB)
  float* a_s      = act + (size_t)NN * HID;        // NN
  float* a_d      = a_s + NN;                      // NN
  unsigned* deg   = (unsigned*)(a_d + NN);         // NN
  unsigned* rowptr= deg + NN;                      // NN
  unsigned* counts= rowptr + NN;                   // M_ (pad to 200704)
  unsigned* bsums = counts + 200704;               // SBLK (pad 256)
  int* es         = (int*)(bsums + 256);           // ET
  float* alpha    = (float*)(es + ET);             // ET
  unsigned* gmax  = (unsigned*)(alpha + ET);       // NG*HID
  float* gsum     = (float*)(gmax + NG * HID);     // NG*HID
  unsigned* cnt   = (unsigned*)(gsum + NG * HID);  // NG
  // pairs staging aliases act (13.6MB <= 25.6MB); consumed (k_bcsr) before
  // act is first written (k_wsum layer 1)
  int2* pairs     = (int2*)act;

  // ---- CSR build via contention-free counting sort (topology shared) ----
  k_cnt  <<<NCH, 256, 0, stream>>>(ei, counts);
  k_scan1<<<SBLK, 256, 0, stream>>>(counts, bsums);
  k_scan2<<<1, 64, 0, stream>>>(bsums);
  k_scan3<<<SBLK, 256, 0, stream>>>(counts, bsums);
  k_place<<<NCH, 256, 0, stream>>>(ei, counts, pairs);
  k_bcsr <<<NBKT, 256, 0, stream>>>(pairs, counts, rowptr, deg, es);

  // ---- layer 1 ----
  k_node1<<<512, 256, 0, stream>>>(x, W1, as1, ad1, h, a_s, a_d);
  k_attn <<<NN / 4, 256, 0, stream>>>(es, rowptr, deg, a_s, a_d, alpha);
  k_wsum <<<NN / 4, 256, 0, stream>>>(es, alpha, rowptr, deg, h, b1, act);

  // ---- layer 2 ----
  k_node2<<<512, 256, 0, stream>>>(act, W2, as2, ad2, h, a_s, a_d);
  k_attn <<<NN / 4, 256, 0, stream>>>(es, rowptr, deg, a_s, a_d, alpha);
  k_wsum <<<NN / 4, 256, 0, stream>>>(es, alpha, rowptr, deg, h, b2, act);

  // ---- pooling + head ----
  hipMemsetAsync(gmax, 0, sizeof(unsigned) * NG * HID, stream);
  hipMemsetAsync(gsum, 0, sizeof(float) * NG * HID, stream);
  hipMemsetAsync(cnt,  0, sizeof(unsigned) * NG, stream);
  k_pool<<<(NN + 255) / 256, 256, 0, stream>>>(act, batch, gmax, gsum, cnt);
  k_final<<<NG / 4, 256, 0, stream>>>(gmax, gsum, cnt, fcw, fcb, out);
}